// Round 14
// baseline (228.759 us; speedup 1.0000x reference)
//
#include <hip/hip_runtime.h>
#include <math.h>

#define L_SEQ   2048
#define NBATCH  2
#define DMODEL  1024
#define DHALF   512
#define DINNER  1024
#define DSTATE  128
#define NHEADS  16
#define HEADDIM 64
#define CONVDIM 1280
#define DINPROJ 2320
#define ROWS    4096   /* NBATCH * L_SEQ */
#define NPADIN  2432   /* DINPROJ padded to multiple of 128 */

#define QCH     64               /* SSD chunk length */
#define NCH     (L_SEQ / QCH)    /* 32 chunks */

typedef __attribute__((ext_vector_type(8))) short bf16x8;
typedef __attribute__((ext_vector_type(4))) float f32x4;

union US8 { uint4 q; unsigned short s[8]; };
union US4 { uint2 q; unsigned short s[4]; };

__device__ __forceinline__ float siluf(float v){ return v / (1.f + expf(-v)); }
__device__ __forceinline__ float softplusf(float v){ return v > 20.f ? v : log1pf(expf(v)); }
__device__ __forceinline__ unsigned short f2bf(float f){
  union { float f; unsigned u; } x; x.f = f;
  unsigned r = (x.u + 0x7fffu + ((x.u >> 16) & 1u)) >> 16;
  return (unsigned short)r;
}
__device__ __forceinline__ float bf2f(unsigned short u){
  union { unsigned u; float f; } x; x.u = ((unsigned)u) << 16; return x.f;
}
__device__ __forceinline__ void gload16(const void* g, void* l){
  __builtin_amdgcn_global_load_lds((const __attribute__((address_space(1))) void*)g,
                                   (__attribute__((address_space(3))) void*)l, 16, 0, 0);
}
__device__ __forceinline__ int kx(int row){ return ((row ^ (row >> 3)) & 7) << 3; }
__device__ __forceinline__ int sw4(int row){ return (row ^ (row >> 2)) & 3; }

__device__ __forceinline__ float blockReduceSum256(float v, float* red){
  #pragma unroll
  for (int o = 32; o > 0; o >>= 1) v += __shfl_xor(v, o);
  int wid = threadIdx.x >> 6, lane = threadIdx.x & 63;
  if (lane == 0) red[wid] = v;
  __syncthreads();
  return red[0] + red[1] + red[2] + red[3];
}

// ---------------- merged prep: rmsnorm+split (blocks < ROWS) | weight conv (rest) ----
__global__ void prep_kernel(const float* __restrict__ x, const float* __restrict__ nw,
                            unsigned short* __restrict__ uf, unsigned short* __restrict__ ub,
                            const float* __restrict__ s0, const float* __restrict__ s1,
                            const float* __restrict__ s2, const float* __restrict__ s3,
                            const float* __restrict__ s4,
                            unsigned short* __restrict__ d0, unsigned short* __restrict__ d1,
                            unsigned short* __restrict__ d2, unsigned short* __restrict__ d3,
                            unsigned short* __restrict__ d4){
  __shared__ float red[4];
  int tid = threadIdx.x;
  if (blockIdx.x < ROWS){
    int row = blockIdx.x;
    float4 v4 = *(const float4*)(x + (size_t)row*DMODEL + tid*4);
    float ss = v4.x*v4.x + v4.y*v4.y + v4.z*v4.z + v4.w*v4.w;
    ss = blockReduceSum256(ss, red);
    float scale = rsqrtf(ss * (1.f/DMODEL) + 1e-5f);
    int t = row & (L_SEQ-1);
    int fliprow = (row ^ t) | (L_SEQ-1-t);
    float4 w4 = *(const float4*)(nw + tid*4);
    US4 o;
    o.s[0] = f2bf(v4.x*scale*w4.x);
    o.s[1] = f2bf(v4.y*scale*w4.y);
    o.s[2] = f2bf(v4.z*scale*w4.z);
    o.s[3] = f2bf(v4.w*scale*w4.w);
    int d = tid*4;
    if (d < DHALF) *(uint2*)&uf[(size_t)row*DHALF + d] = o.q;
    else           *(uint2*)&ub[(size_t)fliprow*DHALF + (d - DHALF)] = o.q;
    return;
  }
  const int S01 = NPADIN*DHALF;
  const int S23 = DHALF*DINNER;
  const int S4  = DMODEL*DMODEL;
  int idx = ((blockIdx.x - ROWS)*256 + tid)*4;
  const float* s; unsigned short* d; int pad_rows = 0;
  if (idx < S01){ s = s0; d = d0; pad_rows = DINPROJ; }
  else if ((idx -= S01) < S01){ s = s1; d = d1; pad_rows = DINPROJ; }
  else if ((idx -= S01) < S23){ s = s2; d = d2; }
  else if ((idx -= S23) < S23){ s = s3; d = d3; }
  else if ((idx -= S23) < S4){ s = s4; d = d4; }
  else return;
  US4 o;
  if (pad_rows && (idx >> 9) >= pad_rows){
    o.s[0] = o.s[1] = o.s[2] = o.s[3] = 0;
  } else {
    float4 v = *(const float4*)&s[idx];
    o.s[0] = f2bf(v.x); o.s[1] = f2bf(v.y); o.s[2] = f2bf(v.z); o.s[3] = f2bf(v.w);
  }
  *(uint2*)&d[idx] = o.q;
}

// ---------------- bf16 MFMA GEMM: dual-dir, 4-slot deep pipeline (wait-distance 3) ---
template<int TM>
__global__ __launch_bounds__(256) void gemm_bf16_t(
    const unsigned short* __restrict__ A0, const unsigned short* __restrict__ A1, int lda,
    const unsigned short* __restrict__ W0, const unsigned short* __restrict__ W1,
    float* __restrict__ Cf, int ldc,
    const float* __restrict__ bias, const float* __restrict__ res,
    unsigned short* __restrict__ O0a, unsigned short* __restrict__ O0b, int ld0,
    unsigned short* __restrict__ O1a, unsigned short* __restrict__ O1b, int n1, int ld1,
    float* __restrict__ O2a, float* __restrict__ O2b, int n2, int ld2,
    int coff1, int flip1,
    int M, int Nreal, int K){
  constexpr int MI = TM/32;                // m-fragments per wave
  constexpr int QA = TM/64;                // A vmem insts per thread per stage
  constexpr int P = QA + 2;                // total vmem insts per stage (per thread)
  __shared__ unsigned short As[4][TM*32];
  __shared__ unsigned short Bs[4][128*32];
  // XCD-aware swizzle over flattened (z,y,x) grid
  int bid = (blockIdx.z*gridDim.y + blockIdx.y)*gridDim.x + blockIdx.x;
  int nwg = gridDim.x*gridDim.y*gridDim.z;
  int s = bid;
  if ((nwg & 7) == 0){
    int cpx = nwg >> 3;
    s = (bid & 7)*cpx + (bid >> 3);
  }
  int bx = s % gridDim.x;
  int tmp = s / gridDim.x;
  int by = tmp % gridDim.y;
  int dir = tmp / gridDim.y;

  const unsigned short* A = dir ? A1 : A0;
  const unsigned short* W = dir ? W1 : W0;
  unsigned short* O0 = dir ? O0b : O0a;
  unsigned short* O1 = dir ? O1b : O1a;
  float* O2 = dir ? O2b : O2a;
  int coff = dir ? coff1 : 0;
  int flip = dir ? flip1 : 0;

  int bm = by*TM, bn = bx*128;
  int tid = threadIdx.x;
  int lane = tid & 63;
  int wave = tid >> 6;
  int wm = (wave >> 1) * (TM/2), wn = (wave & 1) * 64;
  int l15 = lane & 15, lhi = lane >> 4;

  // hoisted staging pointers (advance via +k0 shorts) and LDS chunk indices
  const unsigned short* pA[QA]; unsigned ldsA[QA];
  #pragma unroll
  for (int q = 0; q < QA; q++){
    int row = (tid >> 2) + q*64;
    pA[q] = A + (size_t)(bm + row)*lda + ((tid & 3) ^ sw4(row))*8;
    ldsA[q] = (unsigned)(tid + q*256)*8;
  }
  const unsigned short* pW[2]; unsigned ldsW[2];
  #pragma unroll
  for (int q = 0; q < 2; q++){
    int row = (tid >> 2) + q*64;
    pW[q] = W + (size_t)(bn + row)*K + ((tid & 3) ^ sw4(row))*8;
    ldsW[q] = (unsigned)(tid + q*256)*8;
  }
  // hoisted fragment LDS offsets (shorts)
  int offA[MI], offB[4];
  #pragma unroll
  for (int i = 0; i < MI; i++){
    int r = wm + i*16 + l15;
    offA[i] = (r*4 + (lhi ^ sw4(r)))*8;
  }
  #pragma unroll
  for (int j = 0; j < 4; j++){
    int r = wn + j*16 + l15;
    offB[j] = (r*4 + (lhi ^ sw4(r)))*8;
  }

  f32x4 acc[MI][4];
  #pragma unroll
  for (int i = 0; i < MI; i++)
    #pragma unroll
    for (int j = 0; j < 4; j++)
      acc[i][j] = (f32x4){0.f,0.f,0.f,0.f};

  auto stage = [&](int sl, int k0){
    #pragma unroll
    for (int q = 0; q < QA; q++) gload16(pA[q] + k0, &As[sl][ldsA[q]]);
    #pragma unroll
    for (int q = 0; q < 2; q++)  gload16(pW[q] + k0, &Bs[sl][ldsW[q]]);
  };

  int NK = K >> 5;                  // >= 16 for all uses
  stage(0, 0);
  stage(1, 32);
  stage(2, 64);
  for (int it = 0; it < NK; ++it){
    int sl = it & 3;
    int rem = NK - 1 - it;          // tiles after current
    if (rem >= 3){
      stage((it + 3) & 3, (it + 3) << 5);
      asm volatile("s_waitcnt vmcnt(%0)" :: "n"(3*P) : "memory");
    } else if (rem == 2){
      asm volatile("s_waitcnt vmcnt(%0)" :: "n"(2*P) : "memory");
    } else if (rem == 1){
      asm volatile("s_waitcnt vmcnt(%0)" :: "n"(P) : "memory");
    } else {
      asm volatile("s_waitcnt vmcnt(0)" ::: "memory");
    }
    asm volatile("s_barrier" ::: "memory");   // tile `it` fully in LDS
    const unsigned short* as = As[sl];
    const unsigned short* bs = Bs[sl];
    bf16x8 af[MI], bfr[4];
    #pragma unroll
    for (int i = 0; i < MI; i++) af[i] = *(const bf16x8*)&as[offA[i]];
    #pragma unroll
    for (int j = 0; j < 4; j++)  bfr[j] = *(const bf16x8*)&bs[offB[j]];
    __builtin_amdgcn_s_setprio(1);
    #pragma unroll
    for (int i = 0; i < MI; i++)
      #pragma unroll
      for (int j = 0; j < 4; j++)
        acc[i][j] = __builtin_amdgcn_mfma_f32_16x16x32_bf16(af[i], bfr[j], acc[i][j], 0, 0, 0);
    __builtin_amdgcn_s_setprio(0);
    asm volatile("s_barrier" ::: "memory");   // slot sl free for restage
  }
  #pragma unroll
  for (int i = 0; i < MI; i++){
    #pragma unroll
    for (int r = 0; r < 4; r++){
      int m = bm + wm + i*16 + lhi*4 + r;
      int mo = m;
      if (flip){ int t = m & (L_SEQ-1); mo = (m ^ t) | (L_SEQ-1-t); }
      #pragma unroll
      for (int j = 0; j < 4; j++){
        int n = bn + wn + j*16 + l15;
        if (n < Nreal){
          float v = acc[i][j][r];
          if (bias) v += bias[n];
          if (res)  v += res[(size_t)mo*ldc + coff + n];
          if (Cf)            Cf[(size_t)mo*ldc + coff + n] = v;
          else if (n < n1)   O0[(size_t)mo*ld0 + coff + n] = f2bf(v);
          else if (n < n2)   O1[(size_t)mo*ld1 + (n - n1)] = f2bf(v);
          else               O2[(size_t)mo*ld2 + (n - n2)] = v;
        }
      }
    }
  }
}

// ---------------- causal depthwise conv (k=4) + silu, bf16 in/out, both dirs/block ---
__global__ void conv_silu_kernel(const unsigned short* __restrict__ xbcf, const unsigned short* __restrict__ xbcb,
                                 const float* __restrict__ cwf, const float* __restrict__ cbf,
                                 const float* __restrict__ cwb, const float* __restrict__ cbb,
                                 unsigned short* __restrict__ cvf, unsigned short* __restrict__ cvb){
  int row = blockIdx.x;
  int tid = threadIdx.x;              // 0..319: dir = tid>=160
  int dir = tid >= 160;
  int slot = tid - dir*160;
  const unsigned short* xbc = dir ? xbcb : xbcf;
  const float* cw = dir ? cwb : cwf;
  const float* cb = dir ? cbb : cbf;
  unsigned short* cv = dir ? cvb : cvf;
  int t = row & (L_SEQ-1);
  int c0 = slot*8;
  const unsigned short* base = xbc + (size_t)row*CONVDIM + c0;
  US8 u3, u2, u1, u0;
  u3.q = *(const uint4*)base;
  u2.q = (t >= 1) ? *(const uint4*)(base - CONVDIM)   : (uint4){0,0,0,0};
  u1.q = (t >= 2) ? *(const uint4*)(base - 2*CONVDIM) : (uint4){0,0,0,0};
  u0.q = (t >= 3) ? *(const uint4*)(base - 3*CONVDIM) : (uint4){0,0,0,0};
  US8 o;
  #pragma unroll
  for (int j = 0; j < 8; j++){
    float4 w = *(const float4*)&cw[(c0+j)*4];
    float v = cb[c0+j];
    v += bf2f(u3.s[j])*w.w + bf2f(u2.s[j])*w.z + bf2f(u1.s[j])*w.y + bf2f(u0.s[j])*w.x;
    o.s[j] = f2bf(siluf(v));
  }
  *(uint4*)&cv[(size_t)row*CONVDIM + c0] = o.q;
}

// ---------------- dt softplus + per-chunk inclusive cumsum of dt*A ----------------
__global__ void dtcum_kernel(const float* __restrict__ drf, const float* __restrict__ drb,
                             const float* __restrict__ dbf, const float* __restrict__ alf,
                             const float* __restrict__ dbb, const float* __restrict__ alb,
                             float* __restrict__ dtf, float* __restrict__ dtb,
                             float* __restrict__ acs){
  int tid = threadIdx.x;
  int wid = blockIdx.x*4 + (tid >> 6);      // 0..2047 = dbh*32 + c
  int tau = tid & 63;
  int c = wid & 31, dbh = wid >> 5;
  int h = dbh & 15, b = (dbh >> 4) & 1, dir = dbh >> 5;
  const float* dr = dir ? drb : drf;
  size_t row = (size_t)b*L_SEQ + c*QCH + tau;
  float raw = dr[row*NHEADS + h];
  float bias = (dir ? dbb : dbf)[h];
  float dtv = softplusf(raw + bias);
  float a = -expf((dir ? alb : alf)[h]);
  (dir ? dtb : dtf)[row*NHEADS + h] = dtv;
  float v = dtv * a;
  #pragma unroll
  for (int off = 1; off < 64; off <<= 1){
    float u = __shfl_up(v, off);
    if (tau >= off) v += u;
  }
  acs[(size_t)dbh*L_SEQ + c*QCH + tau] = v;
}

// ---------------- K_Y (MFMA, fused G): intra Y + chunk-state S^T, per (dir,b,h,chunk)
__global__ __launch_bounds__(256) void intra_kernel(
    const unsigned short* __restrict__ cvf, const unsigned short* __restrict__ cvb,
    const float* __restrict__ dtf, const float* __restrict__ dtb,
    const float* __restrict__ acs,
    float* __restrict__ yf, float* __restrict__ yb,
    unsigned short* __restrict__ S16f, unsigned short* __restrict__ S16b){
  int c = blockIdx.x, dbh = blockIdx.y;
  int h = dbh & 15, b = (dbh >> 4) & 1, dir = dbh >> 5;
  const unsigned short* cv = dir ? cvb : cvf;
  const float* dtp = dir ? dtb : dtf;
  float* y = dir ? yb : yf;
  unsigned short* S16 = dir ? S16b : S16f;
  int tid = threadIdx.x, lane = tid & 63, w = tid >> 6;
  int l15 = lane & 15, lhi = lane >> 4;

  __shared__ __align__(16) unsigned short smem[2*64*128];   // 32KB, phased reuse
  unsigned short* sC   = smem;               // phase1: C[t][n]   (16KB)
  unsigned short* sBr  = smem + 8192;        // phase1: B[s][n]   (16KB)
  unsigned short* sBwT = smem;               // phase2: BwT[n][s] (16KB, overlays sC)
  unsigned short* sGh  = smem + 8192;        // phase3: Gh[t][s]  (8KB, overlays sBr)
  unsigned short* sDxT = smem + 8192 + 4096; // phase3: dxT[p][s] (8KB)
  __shared__ float a_sh[QCH], dt_sh[QCH], w_sh[QCH];

  size_t r0 = (size_t)b*L_SEQ + (size_t)c*QCH;
  if (tid < 64){
    a_sh[tid]  = acs[(size_t)dbh*L_SEQ + c*QCH + tid];
    dt_sh[tid] = dtp[(r0 + tid)*NHEADS + h];
  }
  // stage C and B (row-major, kx chunk swizzle)
  #pragma unroll
  for (int k = 0; k < 4; k++){
    int cid = k*256 + tid;
    int row = cid >> 4, slot = cid & 15;
    US8 ub_, uc_;
    ub_.q = *(const uint4*)&cv[(r0+row)*CONVDIM + DINNER + slot*8];
    uc_.q = *(const uint4*)&cv[(r0+row)*CONVDIM + DINNER + DSTATE + slot*8];
    *(uint4*)&sBr[row*128 + (slot*8 ^ kx(row))] = ub_.q;
    *(uint4*)&sC [row*128 + (slot*8 ^ kx(row))] = uc_.q;
  }
  // x into regs (dxT source)
  US8 xq[2];
  #pragma unroll
  for (int k = 0; k < 2; k++){
    int cid = k*256 + tid;
    int s2 = cid >> 3, p0 = (cid & 7)*8;
    xq[k].q = *(const uint4*)&cv[(r0+s2)*CONVDIM + h*HEADDIM + p0];
  }
  __syncthreads();
  if (tid < 64) w_sh[tid] = expf(a_sh[63] - a_sh[tid]);
  // G[t][s] = sum_n C[t][n]*B[s][n]
  int t0 = w*16;
  bf16x8 cf[4];
  #pragma unroll
  for (int ks = 0; ks < 4; ks++){
    int r = t0 + l15;
    cf[ks] = *(const bf16x8*)&sC[r*128 + ((ks*32 + lhi*8) ^ kx(r))];
  }
  f32x4 accG[4];
  #pragma unroll
  for (int j = 0; j < 4; j++) accG[j] = (f32x4){0.f,0.f,0.f,0.f};
  #pragma unroll
  for (int j = 0; j < 4; j++){
    #pragma unroll
    for (int ks = 0; ks < 4; ks++){
      int r = j*16 + l15;
      bf16x8 wf = *(const bf16x8*)&sBr[r*128 + ((ks*32 + lhi*8) ^ kx(r))];
      accG[j] = __builtin_amdgcn_mfma_f32_16x16x32_bf16(cf[ks], wf, accG[j], 0, 0, 0);
    }
  }
  __syncthreads();   // sC dead -> sBwT region writable; sBr still live
  // BwT[n][s] = w_sh[s]*B[s][n], from LDS
  #pragma unroll
  for (int k = 0; k < 4; k++){
    int cid = k*256 + tid;
    int s2 = cid >> 4, n0 = (cid & 15)*8;
    US8 u; u.q = *(const uint4*)&sBr[s2*128 + (n0 ^ kx(s2))];
    float wv = w_sh[s2];
    #pragma unroll
    for (int j = 0; j < 8; j++){
      int n = n0 + j;
      sBwT[n*64 + (s2 ^ kx(n))] = f2bf(bf2f(u.s[j]) * wv);
    }
  }
  __syncthreads();   // sBr dead -> sGh/sDxT region writable
  // Gh[t][s] = (s<=t) ? G*exp(a[t]-a[s]) : 0 (from accG regs)
  #pragma unroll
  for (int j = 0; j < 4; j++){
    int s2 = j*16 + l15;
    float as2 = a_sh[s2];
    #pragma unroll
    for (int r = 0; r < 4; r++){
      int t = t0 + lhi*4 + r;
      float v = (s2 <= t) ? accG[j][r]*expf(a_sh[t] - as2) : 0.f;
      sGh[t*64 + (s2 ^ kx(t))] = f2bf(v);
    }
  }
  // dxT[p][s] = dt[s]*x[s][p]
  #pragma unroll
  for (int k = 0; k < 2; k++){
    int cid = k*256 + tid;
    int s2 = cid >> 3, p0 = (cid & 7)*8;
    float d = dt_sh[s2];
    #pragma unroll
    for (int j = 0; j < 8; j++){
      int p = p0 + j;
      sDxT[p*64 + (s2 ^ kx(p))] = f2bf(bf2f(xq[k].s[j]) * d);
    }
  }
  __syncthreads();

  bf16x8 aY[2], aS[2];
  #pragma unroll
  for (int ks = 0; ks < 2; ks++){
    int rg = t0 + l15;
    aY[ks] = *(const bf16x8*)&sGh [rg*64 + ((ks*32 + lhi*8) ^ kx(rg))];
    aS[ks] = *(const bf16x8*)&sDxT[rg*64 + ((ks*32 + lhi*8) ^ kx(rg))];
  }
  // Y[t][p] = sum_s Gh[t][s] * dxT[p][s]
  f32x4 accY[4];
  #pragma unroll
  for (int j = 0; j < 4; j++) accY[j] = (f32x4){0.f,0.f,0.f,0.f};
  #pragma unroll
  for (int j = 0; j < 4; j++){
    #pragma unroll
    for (int ks = 0; ks < 2; ks++){
      int rp = j*16 + l15;
      bf16x8 wf = *(const bf16x8*)&sDxT[rp*64 + ((ks*32 + lhi*8) ^ kx(rp))];
      accY[j] = __builtin_amdgcn_mfma_f32_16x16x32_bf16(aY[ks], wf, accY[j], 0, 0, 0);
    }
  }
  // S^T[p][n] = sum_s dxT[p][s] * BwT[n][s]
  f32x4 accS[8];
  #pragma unroll
  for (int j = 0; j < 8; j++) accS[j] = (f32x4){0.f,0.f,0.f,0.f};
  #pragma unroll
  for (int j = 0; j < 8; j++){
    #pragma unroll
    for (int ks = 0; ks < 2; ks++){
      int rn = j*16 + l15;
      bf16x8 wf = *(const bf16x8*)&sBwT[rn*64 + ((ks*32 + lhi*8) ^ kx(rn))];
      accS[j] = __builtin_amdgcn_mfma_f32_16x16x32_bf16(aS[ks], wf, accS[j], 0, 0, 0);
    }
  }
  // epilogues
  #pragma unroll
  for (int j = 0; j < 4; j++){
    #pragma unroll
    for (int r = 0; r < 4; r++){
      int t = t0 + lhi*4 + r, p = j*16 + l15;
      y[(r0 + t)*DINNER + h*HEADDIM + p] = accY[j][r];
    }
  }
  size_t sbase = ((size_t)((b*NHEADS + h)*NCH + c))*8192;
  #pragma unroll
  for (int j = 0; j < 8; j++){
    #pragma unroll
    for (int r = 0; r < 4; r++){
      int p = t0 + lhi*4 + r, n = j*16 + l15;
      S16[sbase + p*128 + n] = f2bf(accS[j][r]);
    }
  }
}

// ---------------- K_S: inter-chunk state recurrence (elementwise over [p][n]) --------
__global__ void chunkscan_kernel(const unsigned short* __restrict__ S16f,
                                 const unsigned short* __restrict__ S16b,
                                 const float* __restrict__ acs,
                                 unsigned short* __restrict__ hin16){
  __shared__ float sa[NCH];
  int tid = threadIdx.x;
  int dbh = blockIdx.x >> 4;
  int e0 = ((blockIdx.x & 15)*256 + tid)*2;
  int bh = dbh & 31, dir = dbh >> 5;
  const unsigned short* S16 = dir ? S16b : S16f;
  if (tid < NCH) sa[tid] = expf(acs[(size_t)dbh*L_SEQ + tid*QCH + 63]);
  __syncthreads();
  float h0 = 0.f, h1 = 0.f;
  #pragma unroll 8
  for (int c = 0; c < NCH; ++c){
    size_t sidx = ((size_t)(bh*NCH + c))*8192 + e0;
    size_t hidx = ((size_t)(dbh*NCH + c))*8192 + e0;
    unsigned sv = *(const unsigned*)&S16[sidx];
    unsigned hv = (unsigned)f2bf(h0) | ((unsigned)f2bf(h1) << 16);
    *(unsigned*)&hin16[hidx] = hv;
    float ea = sa[c];
    h0 = ea*h0 + bf2f((unsigned short)(sv & 0xffff));
    h1 = ea*h1 + bf2f((unsigned short)(sv >> 16));
  }
}

// ---------------- K_I (MFMA): Y = y_intra + e[t]*C·h_in + D*x -> bf16 yg -------------
__global__ __launch_bounds__(256) void inter_kernel(
    const unsigned short* __restrict__ cvf, const unsigned short* __restrict__ cvb,
    const float* __restrict__ acs, const unsigned short* __restrict__ hin16,
    const float* __restrict__ Df, const float* __restrict__ Db,
    const float* __restrict__ yf, const float* __restrict__ yb,
    unsigned short* __restrict__ ygf, unsigned short* __restrict__ ygb){
  int c = blockIdx.x, dbh = blockIdx.y;
  int h = dbh & 15, b = (dbh >> 4) & 1, dir = dbh >> 5;
  const unsigned short* cv = dir ? cvb : cvf;
  const float* y = dir ? yb : yf;
  unsigned short* yg = dir ? ygb : ygf;
  float Dh = (dir ? Db : Df)[h];
  int tid = threadIdx.x, lane = tid & 63, w = tid >> 6;
  int l15 = lane & 15, lhi = lane >> 4;
  __shared__ unsigned short sC [64*128];   // C[t][n]  (A)
  __shared__ unsigned short sHT[64*128];   // hT[p][n] (W)
  __shared__ float e_sh[QCH];
  size_t r0 = (size_t)b*L_SEQ + (size_t)c*QCH;
  size_t hbase = ((size_t)(dbh*NCH + c))*8192;
  if (tid < 64) e_sh[tid] = expf(acs[(size_t)dbh*L_SEQ + c*QCH + tid]);
  #pragma unroll
  for (int k = 0; k < 4; k++){
    int cid = k*256 + tid;
    int row = cid >> 4, slot = cid & 15;
    US8 uc, uh;
    uc.q = *(const uint4*)&cv[(r0+row)*CONVDIM + DINNER + DSTATE + slot*8];
    uh.q = *(const uint4*)&hin16[hbase + cid*8];
    *(uint4*)&sC [row*128 + (slot*8 ^ kx(row))] = uc.q;
    *(uint4*)&sHT[row*128 + (slot*8 ^ kx(row))] = uh.q;
  }
  __syncthreads();
  int t0 = w*16;
  bf16x8 af[4];
  #pragma unroll
  for (int ks = 0; ks < 4; ks++){
    int r = t0 + l15;
    af[ks] = *(const bf16x8*)&sC[r*128 + ((ks*32 + lhi*8) ^ kx(r))];
  }
  f32x4 acc[4];
  #pragma unroll
  for (int j = 0; j < 4; j++) acc[j] = (f32x4){0.f,0.f,0.f,0.f};
  #pragma unroll
  for (int j = 0; j < 4; j++){
    #pragma unroll
    for (int ks = 0; ks < 4; ks++){
      int r = j*16 + l15;
      bf16x8 wf = *(const bf16x8*)&sHT[r*128 + ((ks*32 + lhi*8) ^ kx(r))];
      acc[j] = __builtin_amdgcn_mfma_f32_16x16x32_bf16(af[ks], wf, acc[j], 0, 0, 0);
    }
  }
  #pragma unroll
  for (int j = 0; j < 4; j++){
    #pragma unroll
    for (int r = 0; r < 4; r++){
      int t = t0 + lhi*4 + r, p = j*16 + l15;
      size_t row = r0 + t;
      float xv = bf2f(cv[row*CONVDIM + h*HEADDIM + p]);
      float v = y[row*DINNER + h*HEADDIM + p] + e_sh[t]*acc[j][r] + Dh*xv;
      yg[row*DINNER + h*HEADDIM + p] = f2bf(v);
    }
  }
}

// ---------------- gate (silu(z)) + rmsnorm, all bf16, in place on yg ----------------
__global__ void gate_norm_kernel(unsigned short* __restrict__ ygf, unsigned short* __restrict__ ygb,
                                 const unsigned short* __restrict__ z16f, const unsigned short* __restrict__ z16b,
                                 const float* __restrict__ gwf, const float* __restrict__ gwb){
  __shared__ float red[4];
  int row = blockIdx.x; int dir = blockIdx.y;
  int tid = threadIdx.x;
  unsigned short* yg = (dir ? ygb : ygf) + (size_t)row*DINNER;
  const unsigned short* z = (dir ? z16b : z16f) + (size_t)row*DINNER;
  const float* gw = dir ? gwb : gwf;
  int d = tid*4;
  US4 uy, uz;
  uy.q = *(const uint2*)&yg[d];
  uz.q = *(const uint2*)&z[d];
  float v[4]; float ss = 0.f;
  #pragma unroll
  for (int k = 0; k < 4; k++){
    float val = bf2f(uy.s[k]) * siluf(bf2f(uz.s[k]));
    v[k] = val; ss += val*val;
  }
  ss = blockReduceSum256(ss, red);   // __syncthreads inside: reads precede writes
  float scale = rsqrtf(ss*(1.f/DINNER) + 1e-5f);
  float4 w4 = *(const float4*)&gw[d];
  US4 o;
  o.s[0] = f2bf(v[0]*scale*w4.x);
  o.s[1] = f2bf(v[1]*scale*w4.y);
  o.s[2] = f2bf(v[2]*scale*w4.z);
  o.s[3] = f2bf(v[3]*scale*w4.w);
  *(uint2*)&yg[d] = o.q;
}

extern "C" void kernel_launch(void* const* d_in, const int* in_sizes, int n_in,
                              void* d_out, int out_size, void* d_ws, size_t ws_size,
                              hipStream_t stream) {
  const float* x      = (const float*)d_in[0];
  const float* norm_w = (const float*)d_in[1];
  const float* op_w   = (const float*)d_in[2];
  const float* op_b   = (const float*)d_in[3];
  const float* f_in_w    = (const float*)d_in[4];
  const float* f_conv_w  = (const float*)d_in[5];
  const float* f_conv_b  = (const float*)d_in[6];
  const float* f_dt_bias = (const float*)d_in[7];
  const float* f_A_log   = (const float*)d_in[8];
  const float* f_D       = (const float*)d_in[9];
  const float* f_gnorm_w = (const float*)d_in[10];
  const float* f_outp_w  = (const float*)d_in[11];
  const float* b_in_w    = (const float*)d_in[12];
  const float* b_conv_w  = (const float*)d_in[13];
  const float* b_conv_b  = (const float*)d_in[14];
  const float* b_dt_bias = (const float*)d_in[15];
  const float* b_A_log   = (const float*)d_in[16];
  const float* b_D       = (const float*)d_in[17];
  const float* b_gnorm_w = (const float*)d_in[18];
  const float* b_outp_w  = (const float*)d_in[19];
  float* out = (float*)d_out;

  float* ws = (float*)d_ws;
  size_t off = 0;
  unsigned short* u16f = (unsigned short*)(ws + off);
  unsigned short* u16b = u16f + (size_t)ROWS*DHALF;      off += (size_t)ROWS*DHALF;
  unsigned short* z16f = (unsigned short*)(ws + off);    off += (size_t)ROWS*DINNER/2;
  unsigned short* z16b = (unsigned short*)(ws + off);    off += (size_t)ROWS*DINNER/2;
  unsigned short* xbc16f = (unsigned short*)(ws + off);  off += (size_t)ROWS*CONVDIM/2;
  unsigned short* xbc16b = (unsigned short*)(ws + off);  off += (size_t)ROWS*CONVDIM/2;
  float* draw_f = ws + off; off += (size_t)ROWS*NHEADS;
  float* draw_b = ws + off; off += (size_t)ROWS*NHEADS;
  unsigned short* cv16f = (unsigned short*)(ws + off); off += (size_t)ROWS*CONVDIM/2;
  unsigned short* cv16b = (unsigned short*)(ws + off); off += (size_t)ROWS*CONVDIM/2;
  float* dt_f = ws + off; off += (size_t)ROWS*NHEADS;
  float* dt_b = ws + off; off += (size_t)ROWS*NHEADS;
  float* y_f  = ws + off; off += (size_t)ROWS*DINNER;
  float* y_b  = ws + off; off += (size_t)ROWS*DINNER;
  unsigned short* yg16f = (unsigned short*)(ws + off); off += (size_t)ROWS*DINNER/2;
  unsigned short* yg16b = (unsigned short*)(ws + off); off += (size_t)ROWS*DINNER/2;
  float* acs  = ws + off; off += (size_t)64*L_SEQ;
  unsigned short* S16f = (unsigned short*)(ws + off); off += (size_t)32*NCH*8192/2;
  unsigned short* S16b = (unsigned short*)(ws + off); off += (size_t)32*NCH*8192/2;
  unsigned short* hin16 = (unsigned short*)(ws + off); off += (size_t)64*NCH*8192/2;
  unsigned short* w16_fin  = (unsigned short*)(ws + off); off += (size_t)NPADIN*DHALF/2;
  unsigned short* w16_bin  = (unsigned short*)(ws + off); off += (size_t)NPADIN*DHALF/2;
  unsigned short* w16_fout = (unsigned short*)(ws + off); off += (size_t)DHALF*DINNER/2;
  unsigned short* w16_bout = (unsigned short*)(ws + off); off += (size_t)DHALF*DINNER/2;
  unsigned short* w16_op   = (unsigned short*)(ws + off); off += (size_t)DMODEL*DMODEL/2;
  // cat (bf16 [ROWS][1024]) overlays z16f+z16b region (dead after gate_norm)
  unsigned short* cat16 = z16f;

  // 1. merged prep: rmsnorm+split | weight conversions (one launch)
  {
    const int TOT = 2*NPADIN*DHALF + 2*DHALF*DINNER + DMODEL*DMODEL;
    prep_kernel<<<ROWS + TOT/4/256, 256, 0, stream>>>(
        x, norm_w, u16f, u16b,
        f_in_w, b_in_w, f_outp_w, b_outp_w, op_w,
        w16_fin, w16_bin, w16_fout, w16_bout, w16_op);
  }
  // 2. in-proj GEMM, both dirs, TM=128, 4-slot deep pipeline
  gemm_bf16_t<128><<<dim3(NPADIN/128, ROWS/128, 2), 256, 0, stream>>>(
      u16f, u16b, DHALF, w16_fin, w16_bin,
      nullptr, 0, nullptr, nullptr,
      z16f, z16b, DINNER,
      xbc16f, xbc16b, DINNER, CONVDIM,
      draw_f, draw_b, DINNER+CONVDIM, NHEADS,
      0, 0,
      ROWS, DINPROJ, DHALF);
  // 3. conv + silu (bf16 in/out, both dirs per block)
  conv_silu_kernel<<<ROWS, 320, 0, stream>>>(
      xbc16f, xbc16b, f_conv_w, f_conv_b, b_conv_w, b_conv_b, cv16f, cv16b);
  // 4. dt softplus + chunked cumsum
  dtcum_kernel<<<512, 256, 0, stream>>>(
      draw_f, draw_b, f_dt_bias, f_A_log, b_dt_bias, b_A_log, dt_f, dt_b, acs);
  // 5. SSD: intra (G fused in), chunk recurrence, inter (-> bf16 yg)
  intra_kernel<<<dim3(32, 64), 256, 0, stream>>>(cv16f, cv16b, dt_f, dt_b, acs,
                                                 y_f, y_b, S16f, S16b);
  chunkscan_kernel<<<1024, 256, 0, stream>>>(S16f, S16b, acs, hin16);
  inter_kernel<<<dim3(32, 64), 256, 0, stream>>>(cv16f, cv16b, acs, hin16, f_D, b_D,
                                                 y_f, y_b, yg16f, yg16b);
  // 6. gate + rmsnorm (all bf16, in place on yg)
  gate_norm_kernel<<<dim3(ROWS, 2), 256, 0, stream>>>(
      yg16f, yg16b, z16f, z16b, f_gnorm_w, b_gnorm_w);
  // 7. out-proj GEMM, both dirs -> cat16 (dir1 time-flipped, coff=512); TM=64
  gemm_bf16_t<64><<<dim3(DHALF/128, ROWS/64, 2), 256, 0, stream>>>(
      yg16f, yg16b, DINNER, w16_fout, w16_bout,
      nullptr, 0, nullptr, nullptr,
      cat16, cat16, DMODEL,
      nullptr, nullptr, 1<<30, 0,
      nullptr, nullptr, 1<<30, 0,
      DHALF, 1,
      ROWS, DHALF, DINNER);
  // 8. final projection + bias + residual (fp32 out); TM=64
  gemm_bf16_t<64><<<dim3(DMODEL/128, ROWS/64, 1), 256, 0, stream>>>(
      cat16, nullptr, DMODEL, w16_op, nullptr,
      out, DMODEL, op_b, x,
      nullptr, nullptr, 0,
      nullptr, nullptr, 1<<30, 0,
      nullptr, nullptr, 1<<30, 0,
      0, 0,
      ROWS, DMODEL, DMODEL);
}

// Round 15
// 207.411 us; speedup vs baseline: 1.1029x; 1.1029x over previous
//
#include <hip/hip_runtime.h>
#include <math.h>

#define L_SEQ   2048
#define NBATCH  2
#define DMODEL  1024
#define DHALF   512
#define DINNER  1024
#define DSTATE  128
#define NHEADS  16
#define HEADDIM 64
#define CONVDIM 1280
#define DINPROJ 2320
#define ROWS    4096   /* NBATCH * L_SEQ */
#define NPADIN  2432   /* DINPROJ padded to multiple of 128 */

#define QCH     64               /* SSD chunk length */
#define NCH     (L_SEQ / QCH)    /* 32 chunks */

typedef __attribute__((ext_vector_type(8))) short bf16x8;
typedef __attribute__((ext_vector_type(4))) float f32x4;

union US8 { uint4 q; unsigned short s[8]; };
union US4 { uint2 q; unsigned short s[4]; };

__device__ __forceinline__ float siluf(float v){ return v / (1.f + expf(-v)); }
__device__ __forceinline__ float softplusf(float v){ return v > 20.f ? v : log1pf(expf(v)); }
__device__ __forceinline__ unsigned short f2bf(float f){
  union { float f; unsigned u; } x; x.f = f;
  unsigned r = (x.u + 0x7fffu + ((x.u >> 16) & 1u)) >> 16;
  return (unsigned short)r;
}
__device__ __forceinline__ float bf2f(unsigned short u){
  union { unsigned u; float f; } x; x.u = ((unsigned)u) << 16; return x.f;
}
__device__ __forceinline__ void gload16(const void* g, void* l){
  __builtin_amdgcn_global_load_lds((const __attribute__((address_space(1))) void*)g,
                                   (__attribute__((address_space(3))) void*)l, 16, 0, 0);
}
__device__ __forceinline__ int kx(int row){ return ((row ^ (row >> 3)) & 7) << 3; }
__device__ __forceinline__ int sw4(int row){ return (row ^ (row >> 2)) & 3; }

__device__ __forceinline__ float blockReduceSum256(float v, float* red){
  #pragma unroll
  for (int o = 32; o > 0; o >>= 1) v += __shfl_xor(v, o);
  int wid = threadIdx.x >> 6, lane = threadIdx.x & 63;
  if (lane == 0) red[wid] = v;
  __syncthreads();
  return red[0] + red[1] + red[2] + red[3];
}

// ---------------- merged prep: rmsnorm+split (blocks < ROWS) | weight conv (rest) ----
__global__ void prep_kernel(const float* __restrict__ x, const float* __restrict__ nw,
                            unsigned short* __restrict__ uf, unsigned short* __restrict__ ub,
                            const float* __restrict__ s0, const float* __restrict__ s1,
                            const float* __restrict__ s2, const float* __restrict__ s3,
                            const float* __restrict__ s4,
                            unsigned short* __restrict__ d0, unsigned short* __restrict__ d1,
                            unsigned short* __restrict__ d2, unsigned short* __restrict__ d3,
                            unsigned short* __restrict__ d4){
  __shared__ float red[4];
  int tid = threadIdx.x;
  if (blockIdx.x < ROWS){
    int row = blockIdx.x;
    float4 v4 = *(const float4*)(x + (size_t)row*DMODEL + tid*4);
    float ss = v4.x*v4.x + v4.y*v4.y + v4.z*v4.z + v4.w*v4.w;
    ss = blockReduceSum256(ss, red);
    float scale = rsqrtf(ss * (1.f/DMODEL) + 1e-5f);
    int t = row & (L_SEQ-1);
    int fliprow = (row ^ t) | (L_SEQ-1-t);
    float4 w4 = *(const float4*)(nw + tid*4);
    US4 o;
    o.s[0] = f2bf(v4.x*scale*w4.x);
    o.s[1] = f2bf(v4.y*scale*w4.y);
    o.s[2] = f2bf(v4.z*scale*w4.z);
    o.s[3] = f2bf(v4.w*scale*w4.w);
    int d = tid*4;
    if (d < DHALF) *(uint2*)&uf[(size_t)row*DHALF + d] = o.q;
    else           *(uint2*)&ub[(size_t)fliprow*DHALF + (d - DHALF)] = o.q;
    return;
  }
  const int S01 = NPADIN*DHALF;
  const int S23 = DHALF*DINNER;
  const int S4  = DMODEL*DMODEL;
  int idx = ((blockIdx.x - ROWS)*256 + tid)*4;
  const float* s; unsigned short* d; int pad_rows = 0;
  if (idx < S01){ s = s0; d = d0; pad_rows = DINPROJ; }
  else if ((idx -= S01) < S01){ s = s1; d = d1; pad_rows = DINPROJ; }
  else if ((idx -= S01) < S23){ s = s2; d = d2; }
  else if ((idx -= S23) < S23){ s = s3; d = d3; }
  else if ((idx -= S23) < S4){ s = s4; d = d4; }
  else return;
  US4 o;
  if (pad_rows && (idx >> 9) >= pad_rows){
    o.s[0] = o.s[1] = o.s[2] = o.s[3] = 0;
  } else {
    float4 v = *(const float4*)&s[idx];
    o.s[0] = f2bf(v.x); o.s[1] = f2bf(v.y); o.s[2] = f2bf(v.z); o.s[3] = f2bf(v.w);
  }
  *(uint2*)&d[idx] = o.q;
}

// ---------------- bf16 MFMA GEMM: dual-dir, 3-slot counted-vmcnt (round-11 best) -----
template<int TM>
__global__ __launch_bounds__(256) void gemm_bf16_t(
    const unsigned short* __restrict__ A0, const unsigned short* __restrict__ A1, int lda,
    const unsigned short* __restrict__ W0, const unsigned short* __restrict__ W1,
    float* __restrict__ Cf, int ldc,
    const float* __restrict__ bias, const float* __restrict__ res,
    unsigned short* __restrict__ O0a, unsigned short* __restrict__ O0b, int ld0,
    unsigned short* __restrict__ O1a, unsigned short* __restrict__ O1b, int n1, int ld1,
    float* __restrict__ O2a, float* __restrict__ O2b, int n2, int ld2,
    int coff1, int flip1,
    int M, int Nreal, int K){
  constexpr int MI = TM/32;                // m-fragments per wave
  constexpr int QA = TM/64;                // A vmem insts per thread per stage
  constexpr int P = QA + 2;                // total vmem insts per stage
  __shared__ unsigned short As[3][TM*32];
  __shared__ unsigned short Bs[3][128*32];
  // XCD-aware swizzle over flattened (z,y,x) grid
  int bid = (blockIdx.z*gridDim.y + blockIdx.y)*gridDim.x + blockIdx.x;
  int nwg = gridDim.x*gridDim.y*gridDim.z;
  int s = bid;
  if ((nwg & 7) == 0){
    int cpx = nwg >> 3;
    s = (bid & 7)*cpx + (bid >> 3);
  }
  int bx = s % gridDim.x;
  int tmp = s / gridDim.x;
  int by = tmp % gridDim.y;
  int dir = tmp / gridDim.y;

  const unsigned short* A = dir ? A1 : A0;
  const unsigned short* W = dir ? W1 : W0;
  unsigned short* O0 = dir ? O0b : O0a;
  unsigned short* O1 = dir ? O1b : O1a;
  float* O2 = dir ? O2b : O2a;
  int coff = dir ? coff1 : 0;
  int flip = dir ? flip1 : 0;

  int bm = by*TM, bn = bx*128;
  int tid = threadIdx.x;
  int lane = tid & 63;
  int wave = tid >> 6;
  int wm = (wave >> 1) * (TM/2), wn = (wave & 1) * 64;
  int l15 = lane & 15, lhi = lane >> 4;

  // hoisted staging pointers (advance via +k0 shorts) and LDS chunk indices
  const unsigned short* pA[QA]; unsigned ldsA[QA];
  #pragma unroll
  for (int q = 0; q < QA; q++){
    int row = (tid >> 2) + q*64;
    pA[q] = A + (size_t)(bm + row)*lda + ((tid & 3) ^ sw4(row))*8;
    ldsA[q] = (unsigned)(tid + q*256)*8;
  }
  const unsigned short* pW[2]; unsigned ldsW[2];
  #pragma unroll
  for (int q = 0; q < 2; q++){
    int row = (tid >> 2) + q*64;
    pW[q] = W + (size_t)(bn + row)*K + ((tid & 3) ^ sw4(row))*8;
    ldsW[q] = (unsigned)(tid + q*256)*8;
  }
  // hoisted fragment LDS offsets (shorts)
  int offA[MI], offB[4];
  #pragma unroll
  for (int i = 0; i < MI; i++){
    int r = wm + i*16 + l15;
    offA[i] = (r*4 + (lhi ^ sw4(r)))*8;
  }
  #pragma unroll
  for (int j = 0; j < 4; j++){
    int r = wn + j*16 + l15;
    offB[j] = (r*4 + (lhi ^ sw4(r)))*8;
  }

  f32x4 acc[MI][4];
  #pragma unroll
  for (int i = 0; i < MI; i++)
    #pragma unroll
    for (int j = 0; j < 4; j++)
      acc[i][j] = (f32x4){0.f,0.f,0.f,0.f};

  auto stage = [&](int sl, int k0){
    #pragma unroll
    for (int q = 0; q < QA; q++) gload16(pA[q] + k0, &As[sl][ldsA[q]]);
    #pragma unroll
    for (int q = 0; q < 2; q++)  gload16(pW[q] + k0, &Bs[sl][ldsW[q]]);
  };

  int NK = K >> 5;
  stage(0, 0);
  if (NK > 1) stage(1, 32);
  int sl = 0;
  for (int it = 0; it < NK; ++it){
    if (it + 2 < NK){
      int s2 = sl + 2; if (s2 >= 3) s2 -= 3;
      stage(s2, (it + 2) << 5);
      asm volatile("s_waitcnt vmcnt(%0)" :: "n"(2*P) : "memory");
    } else if (it + 1 < NK){
      asm volatile("s_waitcnt vmcnt(%0)" :: "n"(P) : "memory");
    } else {
      asm volatile("s_waitcnt vmcnt(0)" ::: "memory");
    }
    asm volatile("s_barrier" ::: "memory");   // tile `it` fully in LDS
    const unsigned short* as = As[sl];
    const unsigned short* bs = Bs[sl];
    bf16x8 af[MI], bfr[4];
    #pragma unroll
    for (int i = 0; i < MI; i++) af[i] = *(const bf16x8*)&as[offA[i]];
    #pragma unroll
    for (int j = 0; j < 4; j++)  bfr[j] = *(const bf16x8*)&bs[offB[j]];
    #pragma unroll
    for (int i = 0; i < MI; i++)
      #pragma unroll
      for (int j = 0; j < 4; j++)
        acc[i][j] = __builtin_amdgcn_mfma_f32_16x16x32_bf16(af[i], bfr[j], acc[i][j], 0, 0, 0);
    asm volatile("s_barrier" ::: "memory");   // slot sl free for restage
    sl = (sl + 1 == 3) ? 0 : sl + 1;
  }
  #pragma unroll
  for (int i = 0; i < MI; i++){
    #pragma unroll
    for (int r = 0; r < 4; r++){
      int m = bm + wm + i*16 + lhi*4 + r;
      int mo = m;
      if (flip){ int t = m & (L_SEQ-1); mo = (m ^ t) | (L_SEQ-1-t); }
      #pragma unroll
      for (int j = 0; j < 4; j++){
        int n = bn + wn + j*16 + l15;
        if (n < Nreal){
          float v = acc[i][j][r];
          if (bias) v += bias[n];
          if (res)  v += res[(size_t)mo*ldc + coff + n];
          if (Cf)            Cf[(size_t)mo*ldc + coff + n] = v;
          else if (n < n1)   O0[(size_t)mo*ld0 + coff + n] = f2bf(v);
          else if (n < n2)   O1[(size_t)mo*ld1 + (n - n1)] = f2bf(v);
          else               O2[(size_t)mo*ld2 + (n - n2)] = v;
        }
      }
    }
  }
}

// ---------------- merged: conv+silu (blocks < ROWS) | dt softplus + cumsum (rest) ----
__global__ void convdt_kernel(const unsigned short* __restrict__ xbcf, const unsigned short* __restrict__ xbcb,
                              const float* __restrict__ cwf, const float* __restrict__ cbf,
                              const float* __restrict__ cwb, const float* __restrict__ cbb,
                              unsigned short* __restrict__ cvf, unsigned short* __restrict__ cvb,
                              const float* __restrict__ drf, const float* __restrict__ drb,
                              const float* __restrict__ dbf, const float* __restrict__ alf,
                              const float* __restrict__ dbb, const float* __restrict__ alb,
                              float* __restrict__ dtf, float* __restrict__ dtb,
                              float* __restrict__ acs){
  int tid = threadIdx.x;
  if (blockIdx.x < ROWS){
    int row = blockIdx.x;
    int dir = tid >= 160;
    int slot = tid - dir*160;
    const unsigned short* xbc = dir ? xbcb : xbcf;
    const float* cw = dir ? cwb : cwf;
    const float* cb = dir ? cbb : cbf;
    unsigned short* cv = dir ? cvb : cvf;
    int t = row & (L_SEQ-1);
    int c0 = slot*8;
    const unsigned short* base = xbc + (size_t)row*CONVDIM + c0;
    US8 u3, u2, u1, u0;
    u3.q = *(const uint4*)base;
    u2.q = (t >= 1) ? *(const uint4*)(base - CONVDIM)   : (uint4){0,0,0,0};
    u1.q = (t >= 2) ? *(const uint4*)(base - 2*CONVDIM) : (uint4){0,0,0,0};
    u0.q = (t >= 3) ? *(const uint4*)(base - 3*CONVDIM) : (uint4){0,0,0,0};
    US8 o;
    #pragma unroll
    for (int j = 0; j < 8; j++){
      float4 w = *(const float4*)&cw[(c0+j)*4];
      float v = cb[c0+j];
      v += bf2f(u3.s[j])*w.w + bf2f(u2.s[j])*w.z + bf2f(u1.s[j])*w.y + bf2f(u0.s[j])*w.x;
      o.s[j] = f2bf(siluf(v));
    }
    *(uint4*)&cv[(size_t)row*CONVDIM + c0] = o.q;
    return;
  }
  if (tid >= 256) return;
  int wid = (blockIdx.x - ROWS)*4 + (tid >> 6);   // 0..2047 = dbh*32 + c
  int tau = tid & 63;
  int c = wid & 31, dbh = wid >> 5;
  int h = dbh & 15, b = (dbh >> 4) & 1, dir = dbh >> 5;
  const float* dr = dir ? drb : drf;
  size_t row = (size_t)b*L_SEQ + c*QCH + tau;
  float raw = dr[row*NHEADS + h];
  float bias = (dir ? dbb : dbf)[h];
  float dtv = softplusf(raw + bias);
  float a = -expf((dir ? alb : alf)[h]);
  (dir ? dtb : dtf)[row*NHEADS + h] = dtv;
  float v = dtv * a;
  #pragma unroll
  for (int off = 1; off < 64; off <<= 1){
    float u = __shfl_up(v, off);
    if (tau >= off) v += u;
  }
  acs[(size_t)dbh*L_SEQ + c*QCH + tau] = v;
}

// ---------------- K_Y (MFMA, fused G): intra Y(bf16) + chunk-state S^T --------------
__global__ __launch_bounds__(256) void intra_kernel(
    const unsigned short* __restrict__ cvf, const unsigned short* __restrict__ cvb,
    const float* __restrict__ dtf, const float* __restrict__ dtb,
    const float* __restrict__ acs,
    unsigned short* __restrict__ y16f, unsigned short* __restrict__ y16b,
    unsigned short* __restrict__ S16f, unsigned short* __restrict__ S16b){
  int c = blockIdx.x, dbh = blockIdx.y;
  int h = dbh & 15, b = (dbh >> 4) & 1, dir = dbh >> 5;
  const unsigned short* cv = dir ? cvb : cvf;
  const float* dtp = dir ? dtb : dtf;
  unsigned short* y16 = dir ? y16b : y16f;
  unsigned short* S16 = dir ? S16b : S16f;
  int tid = threadIdx.x, lane = tid & 63, w = tid >> 6;
  int l15 = lane & 15, lhi = lane >> 4;

  __shared__ __align__(16) unsigned short smem[2*64*128];   // 32KB, phased reuse
  unsigned short* sC   = smem;               // phase1: C[t][n]   (16KB)
  unsigned short* sBr  = smem + 8192;        // phase1: B[s][n]   (16KB)
  unsigned short* sBwT = smem;               // phase2: BwT[n][s] (16KB, overlays sC)
  unsigned short* sGh  = smem + 8192;        // phase3: Gh[t][s]  (8KB, overlays sBr)
  unsigned short* sDxT = smem + 8192 + 4096; // phase3: dxT[p][s] (8KB)
  __shared__ float a_sh[QCH], dt_sh[QCH], w_sh[QCH];

  size_t r0 = (size_t)b*L_SEQ + (size_t)c*QCH;
  if (tid < 64){
    a_sh[tid]  = acs[(size_t)dbh*L_SEQ + c*QCH + tid];
    dt_sh[tid] = dtp[(r0 + tid)*NHEADS + h];
  }
  // stage C and B (row-major, kx chunk swizzle)
  #pragma unroll
  for (int k = 0; k < 4; k++){
    int cid = k*256 + tid;
    int row = cid >> 4, slot = cid & 15;
    US8 ub_, uc_;
    ub_.q = *(const uint4*)&cv[(r0+row)*CONVDIM + DINNER + slot*8];
    uc_.q = *(const uint4*)&cv[(r0+row)*CONVDIM + DINNER + DSTATE + slot*8];
    *(uint4*)&sBr[row*128 + (slot*8 ^ kx(row))] = ub_.q;
    *(uint4*)&sC [row*128 + (slot*8 ^ kx(row))] = uc_.q;
  }
  // x into regs (dxT source)
  US8 xq[2];
  #pragma unroll
  for (int k = 0; k < 2; k++){
    int cid = k*256 + tid;
    int s2 = cid >> 3, p0 = (cid & 7)*8;
    xq[k].q = *(const uint4*)&cv[(r0+s2)*CONVDIM + h*HEADDIM + p0];
  }
  __syncthreads();
  if (tid < 64) w_sh[tid] = expf(a_sh[63] - a_sh[tid]);
  // G[t][s] = sum_n C[t][n]*B[s][n]
  int t0 = w*16;
  bf16x8 cf[4];
  #pragma unroll
  for (int ks = 0; ks < 4; ks++){
    int r = t0 + l15;
    cf[ks] = *(const bf16x8*)&sC[r*128 + ((ks*32 + lhi*8) ^ kx(r))];
  }
  f32x4 accG[4];
  #pragma unroll
  for (int j = 0; j < 4; j++) accG[j] = (f32x4){0.f,0.f,0.f,0.f};
  #pragma unroll
  for (int j = 0; j < 4; j++){
    #pragma unroll
    for (int ks = 0; ks < 4; ks++){
      int r = j*16 + l15;
      bf16x8 wf = *(const bf16x8*)&sBr[r*128 + ((ks*32 + lhi*8) ^ kx(r))];
      accG[j] = __builtin_amdgcn_mfma_f32_16x16x32_bf16(cf[ks], wf, accG[j], 0, 0, 0);
    }
  }
  __syncthreads();   // sC dead -> sBwT region writable; sBr still live
  // BwT[n][s] = w_sh[s]*B[s][n], from LDS
  #pragma unroll
  for (int k = 0; k < 4; k++){
    int cid = k*256 + tid;
    int s2 = cid >> 4, n0 = (cid & 15)*8;
    US8 u; u.q = *(const uint4*)&sBr[s2*128 + (n0 ^ kx(s2))];
    float wv = w_sh[s2];
    #pragma unroll
    for (int j = 0; j < 8; j++){
      int n = n0 + j;
      sBwT[n*64 + (s2 ^ kx(n))] = f2bf(bf2f(u.s[j]) * wv);
    }
  }
  __syncthreads();   // sBr dead -> sGh/sDxT region writable
  // Gh[t][s] = (s<=t) ? G*exp(a[t]-a[s]) : 0 (from accG regs)
  #pragma unroll
  for (int j = 0; j < 4; j++){
    int s2 = j*16 + l15;
    float as2 = a_sh[s2];
    #pragma unroll
    for (int r = 0; r < 4; r++){
      int t = t0 + lhi*4 + r;
      float v = (s2 <= t) ? accG[j][r]*expf(a_sh[t] - as2) : 0.f;
      sGh[t*64 + (s2 ^ kx(t))] = f2bf(v);
    }
  }
  // dxT[p][s] = dt[s]*x[s][p]
  #pragma unroll
  for (int k = 0; k < 2; k++){
    int cid = k*256 + tid;
    int s2 = cid >> 3, p0 = (cid & 7)*8;
    float d = dt_sh[s2];
    #pragma unroll
    for (int j = 0; j < 8; j++){
      int p = p0 + j;
      sDxT[p*64 + (s2 ^ kx(p))] = f2bf(bf2f(xq[k].s[j]) * d);
    }
  }
  __syncthreads();

  bf16x8 aY[2], aS[2];
  #pragma unroll
  for (int ks = 0; ks < 2; ks++){
    int rg = t0 + l15;
    aY[ks] = *(const bf16x8*)&sGh [rg*64 + ((ks*32 + lhi*8) ^ kx(rg))];
    aS[ks] = *(const bf16x8*)&sDxT[rg*64 + ((ks*32 + lhi*8) ^ kx(rg))];
  }
  // Y[t][p] = sum_s Gh[t][s] * dxT[p][s]
  f32x4 accY[4];
  #pragma unroll
  for (int j = 0; j < 4; j++) accY[j] = (f32x4){0.f,0.f,0.f,0.f};
  #pragma unroll
  for (int j = 0; j < 4; j++){
    #pragma unroll
    for (int ks = 0; ks < 2; ks++){
      int rp = j*16 + l15;
      bf16x8 wf = *(const bf16x8*)&sDxT[rp*64 + ((ks*32 + lhi*8) ^ kx(rp))];
      accY[j] = __builtin_amdgcn_mfma_f32_16x16x32_bf16(aY[ks], wf, accY[j], 0, 0, 0);
    }
  }
  // S^T[p][n] = sum_s dxT[p][s] * BwT[n][s]
  f32x4 accS[8];
  #pragma unroll
  for (int j = 0; j < 8; j++) accS[j] = (f32x4){0.f,0.f,0.f,0.f};
  #pragma unroll
  for (int j = 0; j < 8; j++){
    #pragma unroll
    for (int ks = 0; ks < 2; ks++){
      int rn = j*16 + l15;
      bf16x8 wf = *(const bf16x8*)&sBwT[rn*64 + ((ks*32 + lhi*8) ^ kx(rn))];
      accS[j] = __builtin_amdgcn_mfma_f32_16x16x32_bf16(aS[ks], wf, accS[j], 0, 0, 0);
    }
  }
  // epilogues (y in bf16)
  #pragma unroll
  for (int j = 0; j < 4; j++){
    #pragma unroll
    for (int r = 0; r < 4; r++){
      int t = t0 + lhi*4 + r, p = j*16 + l15;
      y16[(r0 + t)*DINNER + h*HEADDIM + p] = f2bf(accY[j][r]);
    }
  }
  size_t sbase = ((size_t)((b*NHEADS + h)*NCH + c))*8192;
  #pragma unroll
  for (int j = 0; j < 8; j++){
    #pragma unroll
    for (int r = 0; r < 4; r++){
      int p = t0 + lhi*4 + r, n = j*16 + l15;
      S16[sbase + p*128 + n] = f2bf(accS[j][r]);
    }
  }
}

// ---------------- K_S: inter-chunk state recurrence (elementwise over [p][n]) --------
__global__ void chunkscan_kernel(const unsigned short* __restrict__ S16f,
                                 const unsigned short* __restrict__ S16b,
                                 const float* __restrict__ acs,
                                 unsigned short* __restrict__ hin16){
  __shared__ float sa[NCH];
  int tid = threadIdx.x;
  int dbh = blockIdx.x >> 4;
  int e0 = ((blockIdx.x & 15)*256 + tid)*2;
  int bh = dbh & 31, dir = dbh >> 5;
  const unsigned short* S16 = dir ? S16b : S16f;
  if (tid < NCH) sa[tid] = expf(acs[(size_t)dbh*L_SEQ + tid*QCH + 63]);
  __syncthreads();
  float h0 = 0.f, h1 = 0.f;
  #pragma unroll 8
  for (int c = 0; c < NCH; ++c){
    size_t sidx = ((size_t)(bh*NCH + c))*8192 + e0;
    size_t hidx = ((size_t)(dbh*NCH + c))*8192 + e0;
    unsigned sv = *(const unsigned*)&S16[sidx];
    unsigned hv = (unsigned)f2bf(h0) | ((unsigned)f2bf(h1) << 16);
    *(unsigned*)&hin16[hidx] = hv;
    float ea = sa[c];
    h0 = ea*h0 + bf2f((unsigned short)(sv & 0xffff));
    h1 = ea*h1 + bf2f((unsigned short)(sv >> 16));
  }
}

// ---------------- K_I (MFMA): Y = y_intra(bf16) + e[t]*C·h_in + D*x -> bf16 yg -------
__global__ __launch_bounds__(256) void inter_kernel(
    const unsigned short* __restrict__ cvf, const unsigned short* __restrict__ cvb,
    const float* __restrict__ acs, const unsigned short* __restrict__ hin16,
    const float* __restrict__ Df, const float* __restrict__ Db,
    const unsigned short* __restrict__ y16f, const unsigned short* __restrict__ y16b,
    unsigned short* __restrict__ ygf, unsigned short* __restrict__ ygb){
  int c = blockIdx.x, dbh = blockIdx.y;
  int h = dbh & 15, b = (dbh >> 4) & 1, dir = dbh >> 5;
  const unsigned short* cv = dir ? cvb : cvf;
  const unsigned short* y16 = dir ? y16b : y16f;
  unsigned short* yg = dir ? ygb : ygf;
  float Dh = (dir ? Db : Df)[h];
  int tid = threadIdx.x, lane = tid & 63, w = tid >> 6;
  int l15 = lane & 15, lhi = lane >> 4;
  __shared__ unsigned short sC [64*128];   // C[t][n]  (A)
  __shared__ unsigned short sHT[64*128];   // hT[p][n] (W)
  __shared__ float e_sh[QCH];
  size_t r0 = (size_t)b*L_SEQ + (size_t)c*QCH;
  size_t hbase = ((size_t)(dbh*NCH + c))*8192;
  if (tid < 64) e_sh[tid] = expf(acs[(size_t)dbh*L_SEQ + c*QCH + tid]);
  #pragma unroll
  for (int k = 0; k < 4; k++){
    int cid = k*256 + tid;
    int row = cid >> 4, slot = cid & 15;
    US8 uc, uh;
    uc.q = *(const uint4*)&cv[(r0+row)*CONVDIM + DINNER + DSTATE + slot*8];
    uh.q = *(const uint4*)&hin16[hbase + cid*8];
    *(uint4*)&sC [row*128 + (slot*8 ^ kx(row))] = uc.q;
    *(uint4*)&sHT[row*128 + (slot*8 ^ kx(row))] = uh.q;
  }
  __syncthreads();
  int t0 = w*16;
  bf16x8 af[4];
  #pragma unroll
  for (int ks = 0; ks < 4; ks++){
    int r = t0 + l15;
    af[ks] = *(const bf16x8*)&sC[r*128 + ((ks*32 + lhi*8) ^ kx(r))];
  }
  f32x4 acc[4];
  #pragma unroll
  for (int j = 0; j < 4; j++) acc[j] = (f32x4){0.f,0.f,0.f,0.f};
  #pragma unroll
  for (int j = 0; j < 4; j++){
    #pragma unroll
    for (int ks = 0; ks < 4; ks++){
      int r = j*16 + l15;
      bf16x8 wf = *(const bf16x8*)&sHT[r*128 + ((ks*32 + lhi*8) ^ kx(r))];
      acc[j] = __builtin_amdgcn_mfma_f32_16x16x32_bf16(af[ks], wf, acc[j], 0, 0, 0);
    }
  }
  #pragma unroll
  for (int j = 0; j < 4; j++){
    #pragma unroll
    for (int r = 0; r < 4; r++){
      int t = t0 + lhi*4 + r, p = j*16 + l15;
      size_t row = r0 + t;
      float xv = bf2f(cv[row*CONVDIM + h*HEADDIM + p]);
      float v = bf2f(y16[row*DINNER + h*HEADDIM + p]) + e_sh[t]*acc[j][r] + Dh*xv;
      yg[row*DINNER + h*HEADDIM + p] = f2bf(v);
    }
  }
}

// ---------------- gate (silu(z)) + rmsnorm, all bf16, in place on yg ----------------
__global__ void gate_norm_kernel(unsigned short* __restrict__ ygf, unsigned short* __restrict__ ygb,
                                 const unsigned short* __restrict__ z16f, const unsigned short* __restrict__ z16b,
                                 const float* __restrict__ gwf, const float* __restrict__ gwb){
  __shared__ float red[4];
  int row = blockIdx.x; int dir = blockIdx.y;
  int tid = threadIdx.x;
  unsigned short* yg = (dir ? ygb : ygf) + (size_t)row*DINNER;
  const unsigned short* z = (dir ? z16b : z16f) + (size_t)row*DINNER;
  const float* gw = dir ? gwb : gwf;
  int d = tid*4;
  US4 uy, uz;
  uy.q = *(const uint2*)&yg[d];
  uz.q = *(const uint2*)&z[d];
  float v[4]; float ss = 0.f;
  #pragma unroll
  for (int k = 0; k < 4; k++){
    float val = bf2f(uy.s[k]) * siluf(bf2f(uz.s[k]));
    v[k] = val; ss += val*val;
  }
  ss = blockReduceSum256(ss, red);   // __syncthreads inside: reads precede writes
  float scale = rsqrtf(ss*(1.f/DINNER) + 1e-5f);
  float4 w4 = *(const float4*)&gw[d];
  US4 o;
  o.s[0] = f2bf(v[0]*scale*w4.x);
  o.s[1] = f2bf(v[1]*scale*w4.y);
  o.s[2] = f2bf(v[2]*scale*w4.z);
  o.s[3] = f2bf(v[3]*scale*w4.w);
  *(uint2*)&yg[d] = o.q;
}

extern "C" void kernel_launch(void* const* d_in, const int* in_sizes, int n_in,
                              void* d_out, int out_size, void* d_ws, size_t ws_size,
                              hipStream_t stream) {
  const float* x      = (const float*)d_in[0];
  const float* norm_w = (const float*)d_in[1];
  const float* op_w   = (const float*)d_in[2];
  const float* op_b   = (const float*)d_in[3];
  const float* f_in_w    = (const float*)d_in[4];
  const float* f_conv_w  = (const float*)d_in[5];
  const float* f_conv_b  = (const float*)d_in[6];
  const float* f_dt_bias = (const float*)d_in[7];
  const float* f_A_log   = (const float*)d_in[8];
  const float* f_D       = (const float*)d_in[9];
  const float* f_gnorm_w = (const float*)d_in[10];
  const float* f_outp_w  = (const float*)d_in[11];
  const float* b_in_w    = (const float*)d_in[12];
  const float* b_conv_w  = (const float*)d_in[13];
  const float* b_conv_b  = (const float*)d_in[14];
  const float* b_dt_bias = (const float*)d_in[15];
  const float* b_A_log   = (const float*)d_in[16];
  const float* b_D       = (const float*)d_in[17];
  const float* b_gnorm_w = (const float*)d_in[18];
  const float* b_outp_w  = (const float*)d_in[19];
  float* out = (float*)d_out;

  float* ws = (float*)d_ws;
  size_t off = 0;
  unsigned short* u16f = (unsigned short*)(ws + off);
  unsigned short* u16b = u16f + (size_t)ROWS*DHALF;      off += (size_t)ROWS*DHALF;
  unsigned short* z16f = (unsigned short*)(ws + off);    off += (size_t)ROWS*DINNER/2;
  unsigned short* z16b = (unsigned short*)(ws + off);    off += (size_t)ROWS*DINNER/2;
  unsigned short* xbc16f = (unsigned short*)(ws + off);  off += (size_t)ROWS*CONVDIM/2;
  unsigned short* xbc16b = (unsigned short*)(ws + off);  off += (size_t)ROWS*CONVDIM/2;
  float* draw_f = ws + off; off += (size_t)ROWS*NHEADS;
  float* draw_b = ws + off; off += (size_t)ROWS*NHEADS;
  unsigned short* cv16f = (unsigned short*)(ws + off); off += (size_t)ROWS*CONVDIM/2;
  unsigned short* cv16b = (unsigned short*)(ws + off); off += (size_t)ROWS*CONVDIM/2;
  float* dt_f = ws + off; off += (size_t)ROWS*NHEADS;
  float* dt_b = ws + off; off += (size_t)ROWS*NHEADS;
  unsigned short* y16f = (unsigned short*)(ws + off); off += (size_t)ROWS*DINNER/2;
  unsigned short* y16b = (unsigned short*)(ws + off); off += (size_t)ROWS*DINNER/2;
  unsigned short* yg16f = (unsigned short*)(ws + off); off += (size_t)ROWS*DINNER/2;
  unsigned short* yg16b = (unsigned short*)(ws + off); off += (size_t)ROWS*DINNER/2;
  float* acs  = ws + off; off += (size_t)64*L_SEQ;
  unsigned short* S16f = (unsigned short*)(ws + off); off += (size_t)32*NCH*8192/2;
  unsigned short* S16b = (unsigned short*)(ws + off); off += (size_t)32*NCH*8192/2;
  unsigned short* hin16 = (unsigned short*)(ws + off); off += (size_t)64*NCH*8192/2;
  unsigned short* w16_fin  = (unsigned short*)(ws + off); off += (size_t)NPADIN*DHALF/2;
  unsigned short* w16_bin  = (unsigned short*)(ws + off); off += (size_t)NPADIN*DHALF/2;
  unsigned short* w16_fout = (unsigned short*)(ws + off); off += (size_t)DHALF*DINNER/2;
  unsigned short* w16_bout = (unsigned short*)(ws + off); off += (size_t)DHALF*DINNER/2;
  unsigned short* w16_op   = (unsigned short*)(ws + off); off += (size_t)DMODEL*DMODEL/2;
  // cat (bf16 [ROWS][1024]) overlays z16f+z16b region (dead after gate_norm)
  unsigned short* cat16 = z16f;

  // 1. merged prep: rmsnorm+split | weight conversions (one launch)
  {
    const int TOT = 2*NPADIN*DHALF + 2*DHALF*DINNER + DMODEL*DMODEL;
    prep_kernel<<<ROWS + TOT/4/256, 256, 0, stream>>>(
        x, norm_w, u16f, u16b,
        f_in_w, b_in_w, f_outp_w, b_outp_w, op_w,
        w16_fin, w16_bin, w16_fout, w16_bout, w16_op);
  }
  // 2. in-proj GEMM, both dirs, TM=128 (round-11 best config)
  gemm_bf16_t<128><<<dim3(NPADIN/128, ROWS/128, 2), 256, 0, stream>>>(
      u16f, u16b, DHALF, w16_fin, w16_bin,
      nullptr, 0, nullptr, nullptr,
      z16f, z16b, DINNER,
      xbc16f, xbc16b, DINNER, CONVDIM,
      draw_f, draw_b, DINNER+CONVDIM, NHEADS,
      0, 0,
      ROWS, DINPROJ, DHALF);
  // 3. merged conv+silu | dt softplus + chunked cumsum (one launch)
  convdt_kernel<<<ROWS + 512, 320, 0, stream>>>(
      xbc16f, xbc16b, f_conv_w, f_conv_b, b_conv_w, b_conv_b, cv16f, cv16b,
      draw_f, draw_b, f_dt_bias, f_A_log, b_dt_bias, b_A_log, dt_f, dt_b, acs);
  // 4. SSD: intra (G fused in, y bf16), chunk recurrence, inter (-> bf16 yg)
  intra_kernel<<<dim3(32, 64), 256, 0, stream>>>(cv16f, cv16b, dt_f, dt_b, acs,
                                                 y16f, y16b, S16f, S16b);
  chunkscan_kernel<<<1024, 256, 0, stream>>>(S16f, S16b, acs, hin16);
  inter_kernel<<<dim3(32, 64), 256, 0, stream>>>(cv16f, cv16b, acs, hin16, f_D, b_D,
                                                 y16f, y16b, yg16f, yg16b);
  // 5. gate + rmsnorm (all bf16, in place on yg)
  gate_norm_kernel<<<dim3(ROWS, 2), 256, 0, stream>>>(
      yg16f, yg16b, z16f, z16b, f_gnorm_w, b_gnorm_w);
  // 6. out-proj GEMM, both dirs -> cat16 (dir1 time-flipped, coff=512); TM=64
  gemm_bf16_t<64><<<dim3(DHALF/128, ROWS/64, 2), 256, 0, stream>>>(
      yg16f, yg16b, DINNER, w16_fout, w16_bout,
      nullptr, 0, nullptr, nullptr,
      cat16, cat16, DMODEL,
      nullptr, nullptr, 1<<30, 0,
      nullptr, nullptr, 1<<30, 0,
      DHALF, 1,
      ROWS, DHALF, DINNER);
  // 7. final projection + bias + residual (fp32 out); TM=64
  gemm_bf16_t<64><<<dim3(DMODEL/128, ROWS/64, 1), 256, 0, stream>>>(
      cat16, nullptr, DMODEL, w16_op, nullptr,
      out, DMODEL, op_b, x,
      nullptr, nullptr, 0,
      nullptr, nullptr, 1<<30, 0,
      nullptr, nullptr, 1<<30, 0,
      0, 0,
      ROWS, DMODEL, DMODEL);
}

// Round 16
// 206.443 us; speedup vs baseline: 1.1081x; 1.0047x over previous
//
#include <hip/hip_runtime.h>
#include <math.h>

#define L_SEQ   2048
#define NBATCH  2
#define DMODEL  1024
#define DHALF   512
#define DINNER  1024
#define DSTATE  128
#define NHEADS  16
#define HEADDIM 64
#define CONVDIM 1280
#define DINPROJ 2320
#define ROWS    4096   /* NBATCH * L_SEQ */
#define NPADIN  2432   /* DINPROJ padded to multiple of 128 */

#define QCH     64               /* SSD chunk length */
#define NCH     (L_SEQ / QCH)    /* 32 chunks */

typedef __attribute__((ext_vector_type(8))) short bf16x8;
typedef __attribute__((ext_vector_type(4))) float f32x4;

union US8 { uint4 q; unsigned short s[8]; };
union US4 { uint2 q; unsigned short s[4]; };

__device__ __forceinline__ float siluf(float v){ return v / (1.f + expf(-v)); }
__device__ __forceinline__ float softplusf(float v){ return v > 20.f ? v : log1pf(expf(v)); }
__device__ __forceinline__ unsigned short f2bf(float f){
  union { float f; unsigned u; } x; x.f = f;
  unsigned r = (x.u + 0x7fffu + ((x.u >> 16) & 1u)) >> 16;
  return (unsigned short)r;
}
__device__ __forceinline__ float bf2f(unsigned short u){
  union { unsigned u; float f; } x; x.u = ((unsigned)u) << 16; return x.f;
}
__device__ __forceinline__ void gload16(const void* g, void* l){
  __builtin_amdgcn_global_load_lds((const __attribute__((address_space(1))) void*)g,
                                   (__attribute__((address_space(3))) void*)l, 16, 0, 0);
}
__device__ __forceinline__ int kx(int row){ return ((row ^ (row >> 3)) & 7) << 3; }
__device__ __forceinline__ int sw4(int row){ return (row ^ (row >> 2)) & 3; }

__device__ __forceinline__ float blockReduceSum256(float v, float* red){
  #pragma unroll
  for (int o = 32; o > 0; o >>= 1) v += __shfl_xor(v, o);
  int wid = threadIdx.x >> 6, lane = threadIdx.x & 63;
  if (lane == 0) red[wid] = v;
  __syncthreads();
  return red[0] + red[1] + red[2] + red[3];
}

// ---------------- merged prep: rmsnorm+split (blocks < ROWS) | weight conv (rest) ----
__global__ void prep_kernel(const float* __restrict__ x, const float* __restrict__ nw,
                            unsigned short* __restrict__ uf, unsigned short* __restrict__ ub,
                            const float* __restrict__ s0, const float* __restrict__ s1,
                            const float* __restrict__ s2, const float* __restrict__ s3,
                            const float* __restrict__ s4,
                            unsigned short* __restrict__ d0, unsigned short* __restrict__ d1,
                            unsigned short* __restrict__ d2, unsigned short* __restrict__ d3,
                            unsigned short* __restrict__ d4){
  __shared__ float red[4];
  int tid = threadIdx.x;
  if (blockIdx.x < ROWS){
    int row = blockIdx.x;
    float4 v4 = *(const float4*)(x + (size_t)row*DMODEL + tid*4);
    float ss = v4.x*v4.x + v4.y*v4.y + v4.z*v4.z + v4.w*v4.w;
    ss = blockReduceSum256(ss, red);
    float scale = rsqrtf(ss * (1.f/DMODEL) + 1e-5f);
    int t = row & (L_SEQ-1);
    int fliprow = (row ^ t) | (L_SEQ-1-t);
    float4 w4 = *(const float4*)(nw + tid*4);
    US4 o;
    o.s[0] = f2bf(v4.x*scale*w4.x);
    o.s[1] = f2bf(v4.y*scale*w4.y);
    o.s[2] = f2bf(v4.z*scale*w4.z);
    o.s[3] = f2bf(v4.w*scale*w4.w);
    int d = tid*4;
    if (d < DHALF) *(uint2*)&uf[(size_t)row*DHALF + d] = o.q;
    else           *(uint2*)&ub[(size_t)fliprow*DHALF + (d - DHALF)] = o.q;
    return;
  }
  const int S01 = NPADIN*DHALF;
  const int S23 = DHALF*DINNER;
  const int S4  = DMODEL*DMODEL;
  int idx = ((blockIdx.x - ROWS)*256 + tid)*4;
  const float* s; unsigned short* d; int pad_rows = 0;
  if (idx < S01){ s = s0; d = d0; pad_rows = DINPROJ; }
  else if ((idx -= S01) < S01){ s = s1; d = d1; pad_rows = DINPROJ; }
  else if ((idx -= S01) < S23){ s = s2; d = d2; }
  else if ((idx -= S23) < S23){ s = s3; d = d3; }
  else if ((idx -= S23) < S4){ s = s4; d = d4; }
  else return;
  US4 o;
  if (pad_rows && (idx >> 9) >= pad_rows){
    o.s[0] = o.s[1] = o.s[2] = o.s[3] = 0;
  } else {
    float4 v = *(const float4*)&s[idx];
    o.s[0] = f2bf(v.x); o.s[1] = f2bf(v.y); o.s[2] = f2bf(v.z); o.s[3] = f2bf(v.w);
  }
  *(uint2*)&d[idx] = o.q;
}

// ---------------- bf16 MFMA GEMM: dual-dir, 3-slot, SINGLE barrier per k-step --------
// Safety: a wave reaching barrier(it) has lgkm-completed its tile-(it-1) ds_reads
// (MFMA issue requires it), so slot (it-1)%3 is dead for ALL waves after barrier(it);
// stage(it+2) into it is race-free. vmcnt(P) at the wait point leaves only stage(it+1)
// outstanding -> tile it guaranteed landed.
template<int TM>
__global__ __launch_bounds__(256) void gemm_bf16_t(
    const unsigned short* __restrict__ A0, const unsigned short* __restrict__ A1, int lda,
    const unsigned short* __restrict__ W0, const unsigned short* __restrict__ W1,
    float* __restrict__ Cf, int ldc,
    const float* __restrict__ bias, const float* __restrict__ res,
    unsigned short* __restrict__ O0a, unsigned short* __restrict__ O0b, int ld0,
    unsigned short* __restrict__ O1a, unsigned short* __restrict__ O1b, int n1, int ld1,
    float* __restrict__ O2a, float* __restrict__ O2b, int n2, int ld2,
    int coff1, int flip1,
    int M, int Nreal, int K){
  constexpr int MI = TM/32;                // m-fragments per wave
  constexpr int QA = TM/64;                // A vmem insts per thread per stage
  constexpr int P = QA + 2;                // total vmem insts per stage
  __shared__ unsigned short As[3][TM*32];
  __shared__ unsigned short Bs[3][128*32];
  // XCD-aware swizzle over flattened (z,y,x) grid
  int bid = (blockIdx.z*gridDim.y + blockIdx.y)*gridDim.x + blockIdx.x;
  int nwg = gridDim.x*gridDim.y*gridDim.z;
  int s = bid;
  if ((nwg & 7) == 0){
    int cpx = nwg >> 3;
    s = (bid & 7)*cpx + (bid >> 3);
  }
  int bx = s % gridDim.x;
  int tmp = s / gridDim.x;
  int by = tmp % gridDim.y;
  int dir = tmp / gridDim.y;

  const unsigned short* A = dir ? A1 : A0;
  const unsigned short* W = dir ? W1 : W0;
  unsigned short* O0 = dir ? O0b : O0a;
  unsigned short* O1 = dir ? O1b : O1a;
  float* O2 = dir ? O2b : O2a;
  int coff = dir ? coff1 : 0;
  int flip = dir ? flip1 : 0;

  int bm = by*TM, bn = bx*128;
  int tid = threadIdx.x;
  int lane = tid & 63;
  int wave = tid >> 6;
  int wm = (wave >> 1) * (TM/2), wn = (wave & 1) * 64;
  int l15 = lane & 15, lhi = lane >> 4;

  // hoisted staging pointers (advance via +k0 shorts) and LDS chunk indices
  const unsigned short* pA[QA]; unsigned ldsA[QA];
  #pragma unroll
  for (int q = 0; q < QA; q++){
    int row = (tid >> 2) + q*64;
    pA[q] = A + (size_t)(bm + row)*lda + ((tid & 3) ^ sw4(row))*8;
    ldsA[q] = (unsigned)(tid + q*256)*8;
  }
  const unsigned short* pW[2]; unsigned ldsW[2];
  #pragma unroll
  for (int q = 0; q < 2; q++){
    int row = (tid >> 2) + q*64;
    pW[q] = W + (size_t)(bn + row)*K + ((tid & 3) ^ sw4(row))*8;
    ldsW[q] = (unsigned)(tid + q*256)*8;
  }
  // hoisted fragment LDS offsets (shorts)
  int offA[MI], offB[4];
  #pragma unroll
  for (int i = 0; i < MI; i++){
    int r = wm + i*16 + l15;
    offA[i] = (r*4 + (lhi ^ sw4(r)))*8;
  }
  #pragma unroll
  for (int j = 0; j < 4; j++){
    int r = wn + j*16 + l15;
    offB[j] = (r*4 + (lhi ^ sw4(r)))*8;
  }

  f32x4 acc[MI][4];
  #pragma unroll
  for (int i = 0; i < MI; i++)
    #pragma unroll
    for (int j = 0; j < 4; j++)
      acc[i][j] = (f32x4){0.f,0.f,0.f,0.f};

  auto stage = [&](int sl, int k0){
    #pragma unroll
    for (int q = 0; q < QA; q++) gload16(pA[q] + k0, &As[sl][ldsA[q]]);
    #pragma unroll
    for (int q = 0; q < 2; q++)  gload16(pW[q] + k0, &Bs[sl][ldsW[q]]);
  };

  int NK = K >> 5;
  stage(0, 0);
  if (NK > 1) stage(1, 32);
  int sl = 0;
  for (int it = 0; it < NK; ++it){
    if (it + 1 < NK){
      asm volatile("s_waitcnt vmcnt(%0)" :: "n"(P) : "memory");
    } else {
      asm volatile("s_waitcnt vmcnt(0)" ::: "memory");
    }
    asm volatile("s_barrier" ::: "memory");   // tile `it` in LDS; slot (it-1)%3 dead
    if (it + 2 < NK){
      int s2 = sl + 2; if (s2 >= 3) s2 -= 3;
      stage(s2, (it + 2) << 5);
    }
    const unsigned short* as = As[sl];
    const unsigned short* bs = Bs[sl];
    bf16x8 af[MI], bfr[4];
    #pragma unroll
    for (int i = 0; i < MI; i++) af[i] = *(const bf16x8*)&as[offA[i]];
    #pragma unroll
    for (int j = 0; j < 4; j++)  bfr[j] = *(const bf16x8*)&bs[offB[j]];
    #pragma unroll
    for (int i = 0; i < MI; i++)
      #pragma unroll
      for (int j = 0; j < 4; j++)
        acc[i][j] = __builtin_amdgcn_mfma_f32_16x16x32_bf16(af[i], bfr[j], acc[i][j], 0, 0, 0);
    sl = (sl + 1 == 3) ? 0 : sl + 1;
  }
  #pragma unroll
  for (int i = 0; i < MI; i++){
    #pragma unroll
    for (int r = 0; r < 4; r++){
      int m = bm + wm + i*16 + lhi*4 + r;
      int mo = m;
      if (flip){ int t = m & (L_SEQ-1); mo = (m ^ t) | (L_SEQ-1-t); }
      #pragma unroll
      for (int j = 0; j < 4; j++){
        int n = bn + wn + j*16 + l15;
        if (n < Nreal){
          float v = acc[i][j][r];
          if (bias) v += bias[n];
          if (res)  v += res[(size_t)mo*ldc + coff + n];
          if (Cf)            Cf[(size_t)mo*ldc + coff + n] = v;
          else if (n < n1)   O0[(size_t)mo*ld0 + coff + n] = f2bf(v);
          else if (n < n2)   O1[(size_t)mo*ld1 + (n - n1)] = f2bf(v);
          else               O2[(size_t)mo*ld2 + (n - n2)] = v;
        }
      }
    }
  }
}

// ---------------- merged: conv+silu (blocks < ROWS) | dt softplus + cumsum (rest) ----
__global__ void convdt_kernel(const unsigned short* __restrict__ xbcf, const unsigned short* __restrict__ xbcb,
                              const float* __restrict__ cwf, const float* __restrict__ cbf,
                              const float* __restrict__ cwb, const float* __restrict__ cbb,
                              unsigned short* __restrict__ cvf, unsigned short* __restrict__ cvb,
                              const float* __restrict__ drf, const float* __restrict__ drb,
                              const float* __restrict__ dbf, const float* __restrict__ alf,
                              const float* __restrict__ dbb, const float* __restrict__ alb,
                              float* __restrict__ dtf, float* __restrict__ dtb,
                              float* __restrict__ acs){
  int tid = threadIdx.x;
  if (blockIdx.x < ROWS){
    int row = blockIdx.x;
    int dir = tid >= 160;
    int slot = tid - dir*160;
    const unsigned short* xbc = dir ? xbcb : xbcf;
    const float* cw = dir ? cwb : cwf;
    const float* cb = dir ? cbb : cbf;
    unsigned short* cv = dir ? cvb : cvf;
    int t = row & (L_SEQ-1);
    int c0 = slot*8;
    const unsigned short* base = xbc + (size_t)row*CONVDIM + c0;
    US8 u3, u2, u1, u0;
    u3.q = *(const uint4*)base;
    u2.q = (t >= 1) ? *(const uint4*)(base - CONVDIM)   : (uint4){0,0,0,0};
    u1.q = (t >= 2) ? *(const uint4*)(base - 2*CONVDIM) : (uint4){0,0,0,0};
    u0.q = (t >= 3) ? *(const uint4*)(base - 3*CONVDIM) : (uint4){0,0,0,0};
    US8 o;
    #pragma unroll
    for (int j = 0; j < 8; j++){
      float4 w = *(const float4*)&cw[(c0+j)*4];
      float v = cb[c0+j];
      v += bf2f(u3.s[j])*w.w + bf2f(u2.s[j])*w.z + bf2f(u1.s[j])*w.y + bf2f(u0.s[j])*w.x;
      o.s[j] = f2bf(siluf(v));
    }
    *(uint4*)&cv[(size_t)row*CONVDIM + c0] = o.q;
    return;
  }
  if (tid >= 256) return;
  int wid = (blockIdx.x - ROWS)*4 + (tid >> 6);   // 0..2047 = dbh*32 + c
  int tau = tid & 63;
  int c = wid & 31, dbh = wid >> 5;
  int h = dbh & 15, b = (dbh >> 4) & 1, dir = dbh >> 5;
  const float* dr = dir ? drb : drf;
  size_t row = (size_t)b*L_SEQ + c*QCH + tau;
  float raw = dr[row*NHEADS + h];
  float bias = (dir ? dbb : dbf)[h];
  float dtv = softplusf(raw + bias);
  float a = -expf((dir ? alb : alf)[h]);
  (dir ? dtb : dtf)[row*NHEADS + h] = dtv;
  float v = dtv * a;
  #pragma unroll
  for (int off = 1; off < 64; off <<= 1){
    float u = __shfl_up(v, off);
    if (tau >= off) v += u;
  }
  acs[(size_t)dbh*L_SEQ + c*QCH + tau] = v;
}

// ---------------- K_Y (MFMA, fused G): intra Y(bf16) + chunk-state S^T --------------
__global__ __launch_bounds__(256) void intra_kernel(
    const unsigned short* __restrict__ cvf, const unsigned short* __restrict__ cvb,
    const float* __restrict__ dtf, const float* __restrict__ dtb,
    const float* __restrict__ acs,
    unsigned short* __restrict__ y16f, unsigned short* __restrict__ y16b,
    unsigned short* __restrict__ S16f, unsigned short* __restrict__ S16b){
  int c = blockIdx.x, dbh = blockIdx.y;
  int h = dbh & 15, b = (dbh >> 4) & 1, dir = dbh >> 5;
  const unsigned short* cv = dir ? cvb : cvf;
  const float* dtp = dir ? dtb : dtf;
  unsigned short* y16 = dir ? y16b : y16f;
  unsigned short* S16 = dir ? S16b : S16f;
  int tid = threadIdx.x, lane = tid & 63, w = tid >> 6;
  int l15 = lane & 15, lhi = lane >> 4;

  __shared__ __align__(16) unsigned short smem[2*64*128];   // 32KB, phased reuse
  unsigned short* sC   = smem;               // phase1: C[t][n]   (16KB)
  unsigned short* sBr  = smem + 8192;        // phase1: B[s][n]   (16KB)
  unsigned short* sBwT = smem;               // phase2: BwT[n][s] (16KB, overlays sC)
  unsigned short* sGh  = smem + 8192;        // phase3: Gh[t][s]  (8KB, overlays sBr)
  unsigned short* sDxT = smem + 8192 + 4096; // phase3: dxT[p][s] (8KB)
  __shared__ float a_sh[QCH], dt_sh[QCH], w_sh[QCH];

  size_t r0 = (size_t)b*L_SEQ + (size_t)c*QCH;
  if (tid < 64){
    a_sh[tid]  = acs[(size_t)dbh*L_SEQ + c*QCH + tid];
    dt_sh[tid] = dtp[(r0 + tid)*NHEADS + h];
  }
  // stage C and B (row-major, kx chunk swizzle)
  #pragma unroll
  for (int k = 0; k < 4; k++){
    int cid = k*256 + tid;
    int row = cid >> 4, slot = cid & 15;
    US8 ub_, uc_;
    ub_.q = *(const uint4*)&cv[(r0+row)*CONVDIM + DINNER + slot*8];
    uc_.q = *(const uint4*)&cv[(r0+row)*CONVDIM + DINNER + DSTATE + slot*8];
    *(uint4*)&sBr[row*128 + (slot*8 ^ kx(row))] = ub_.q;
    *(uint4*)&sC [row*128 + (slot*8 ^ kx(row))] = uc_.q;
  }
  // x into regs (dxT source)
  US8 xq[2];
  #pragma unroll
  for (int k = 0; k < 2; k++){
    int cid = k*256 + tid;
    int s2 = cid >> 3, p0 = (cid & 7)*8;
    xq[k].q = *(const uint4*)&cv[(r0+s2)*CONVDIM + h*HEADDIM + p0];
  }
  __syncthreads();
  if (tid < 64) w_sh[tid] = expf(a_sh[63] - a_sh[tid]);
  // G[t][s] = sum_n C[t][n]*B[s][n]
  int t0 = w*16;
  bf16x8 cf[4];
  #pragma unroll
  for (int ks = 0; ks < 4; ks++){
    int r = t0 + l15;
    cf[ks] = *(const bf16x8*)&sC[r*128 + ((ks*32 + lhi*8) ^ kx(r))];
  }
  f32x4 accG[4];
  #pragma unroll
  for (int j = 0; j < 4; j++) accG[j] = (f32x4){0.f,0.f,0.f,0.f};
  #pragma unroll
  for (int j = 0; j < 4; j++){
    #pragma unroll
    for (int ks = 0; ks < 4; ks++){
      int r = j*16 + l15;
      bf16x8 wf = *(const bf16x8*)&sBr[r*128 + ((ks*32 + lhi*8) ^ kx(r))];
      accG[j] = __builtin_amdgcn_mfma_f32_16x16x32_bf16(cf[ks], wf, accG[j], 0, 0, 0);
    }
  }
  __syncthreads();   // sC dead -> sBwT region writable; sBr still live
  // BwT[n][s] = w_sh[s]*B[s][n], from LDS
  #pragma unroll
  for (int k = 0; k < 4; k++){
    int cid = k*256 + tid;
    int s2 = cid >> 4, n0 = (cid & 15)*8;
    US8 u; u.q = *(const uint4*)&sBr[s2*128 + (n0 ^ kx(s2))];
    float wv = w_sh[s2];
    #pragma unroll
    for (int j = 0; j < 8; j++){
      int n = n0 + j;
      sBwT[n*64 + (s2 ^ kx(n))] = f2bf(bf2f(u.s[j]) * wv);
    }
  }
  __syncthreads();   // sBr dead -> sGh/sDxT region writable
  // Gh[t][s] = (s<=t) ? G*exp(a[t]-a[s]) : 0 (from accG regs)
  #pragma unroll
  for (int j = 0; j < 4; j++){
    int s2 = j*16 + l15;
    float as2 = a_sh[s2];
    #pragma unroll
    for (int r = 0; r < 4; r++){
      int t = t0 + lhi*4 + r;
      float v = (s2 <= t) ? accG[j][r]*expf(a_sh[t] - as2) : 0.f;
      sGh[t*64 + (s2 ^ kx(t))] = f2bf(v);
    }
  }
  // dxT[p][s] = dt[s]*x[s][p]
  #pragma unroll
  for (int k = 0; k < 2; k++){
    int cid = k*256 + tid;
    int s2 = cid >> 3, p0 = (cid & 7)*8;
    float d = dt_sh[s2];
    #pragma unroll
    for (int j = 0; j < 8; j++){
      int p = p0 + j;
      sDxT[p*64 + (s2 ^ kx(p))] = f2bf(bf2f(xq[k].s[j]) * d);
    }
  }
  __syncthreads();

  bf16x8 aY[2], aS[2];
  #pragma unroll
  for (int ks = 0; ks < 2; ks++){
    int rg = t0 + l15;
    aY[ks] = *(const bf16x8*)&sGh [rg*64 + ((ks*32 + lhi*8) ^ kx(rg))];
    aS[ks] = *(const bf16x8*)&sDxT[rg*64 + ((ks*32 + lhi*8) ^ kx(rg))];
  }
  // Y[t][p] = sum_s Gh[t][s] * dxT[p][s]
  f32x4 accY[4];
  #pragma unroll
  for (int j = 0; j < 4; j++) accY[j] = (f32x4){0.f,0.f,0.f,0.f};
  #pragma unroll
  for (int j = 0; j < 4; j++){
    #pragma unroll
    for (int ks = 0; ks < 2; ks++){
      int rp = j*16 + l15;
      bf16x8 wf = *(const bf16x8*)&sDxT[rp*64 + ((ks*32 + lhi*8) ^ kx(rp))];
      accY[j] = __builtin_amdgcn_mfma_f32_16x16x32_bf16(aY[ks], wf, accY[j], 0, 0, 0);
    }
  }
  // S^T[p][n] = sum_s dxT[p][s] * BwT[n][s]
  f32x4 accS[8];
  #pragma unroll
  for (int j = 0; j < 8; j++) accS[j] = (f32x4){0.f,0.f,0.f,0.f};
  #pragma unroll
  for (int j = 0; j < 8; j++){
    #pragma unroll
    for (int ks = 0; ks < 2; ks++){
      int rn = j*16 + l15;
      bf16x8 wf = *(const bf16x8*)&sBwT[rn*64 + ((ks*32 + lhi*8) ^ kx(rn))];
      accS[j] = __builtin_amdgcn_mfma_f32_16x16x32_bf16(aS[ks], wf, accS[j], 0, 0, 0);
    }
  }
  // epilogues (y in bf16)
  #pragma unroll
  for (int j = 0; j < 4; j++){
    #pragma unroll
    for (int r = 0; r < 4; r++){
      int t = t0 + lhi*4 + r, p = j*16 + l15;
      y16[(r0 + t)*DINNER + h*HEADDIM + p] = f2bf(accY[j][r]);
    }
  }
  size_t sbase = ((size_t)((b*NHEADS + h)*NCH + c))*8192;
  #pragma unroll
  for (int j = 0; j < 8; j++){
    #pragma unroll
    for (int r = 0; r < 4; r++){
      int p = t0 + lhi*4 + r, n = j*16 + l15;
      S16[sbase + p*128 + n] = f2bf(accS[j][r]);
    }
  }
}

// ---------------- K_S: inter-chunk state recurrence, uint4-vectorized ----------------
__global__ void chunkscan_kernel(const unsigned short* __restrict__ S16f,
                                 const unsigned short* __restrict__ S16b,
                                 const float* __restrict__ acs,
                                 unsigned short* __restrict__ hin16){
  __shared__ float sa[NCH];
  int tid = threadIdx.x;
  int dbh = blockIdx.x >> 2;                   // 256 blocks: 4 per dbh
  int e0 = ((blockIdx.x & 3)*256 + tid)*8;     // 8 bf16 per thread
  int bh = dbh & 31, dir = dbh >> 5;
  const unsigned short* S16 = dir ? S16b : S16f;
  if (tid < NCH) sa[tid] = expf(acs[(size_t)dbh*L_SEQ + tid*QCH + 63]);
  __syncthreads();
  float h0=0.f,h1=0.f,h2=0.f,h3=0.f,h4=0.f,h5=0.f,h6=0.f,h7=0.f;
  #pragma unroll 4
  for (int c = 0; c < NCH; ++c){
    size_t sidx = ((size_t)(bh*NCH + c))*8192 + e0;
    size_t hidx = ((size_t)(dbh*NCH + c))*8192 + e0;
    US8 sv; sv.q = *(const uint4*)&S16[sidx];
    US8 hv;
    hv.s[0]=f2bf(h0); hv.s[1]=f2bf(h1); hv.s[2]=f2bf(h2); hv.s[3]=f2bf(h3);
    hv.s[4]=f2bf(h4); hv.s[5]=f2bf(h5); hv.s[6]=f2bf(h6); hv.s[7]=f2bf(h7);
    *(uint4*)&hin16[hidx] = hv.q;
    float ea = sa[c];
    h0 = ea*h0 + bf2f(sv.s[0]); h1 = ea*h1 + bf2f(sv.s[1]);
    h2 = ea*h2 + bf2f(sv.s[2]); h3 = ea*h3 + bf2f(sv.s[3]);
    h4 = ea*h4 + bf2f(sv.s[4]); h5 = ea*h5 + bf2f(sv.s[5]);
    h6 = ea*h6 + bf2f(sv.s[6]); h7 = ea*h7 + bf2f(sv.s[7]);
  }
}

// ---------------- K_I (MFMA): Y = y_intra(bf16) + e[t]*C·h_in + D*x -> bf16 yg -------
__global__ __launch_bounds__(256) void inter_kernel(
    const unsigned short* __restrict__ cvf, const unsigned short* __restrict__ cvb,
    const float* __restrict__ acs, const unsigned short* __restrict__ hin16,
    const float* __restrict__ Df, const float* __restrict__ Db,
    const unsigned short* __restrict__ y16f, const unsigned short* __restrict__ y16b,
    unsigned short* __restrict__ ygf, unsigned short* __restrict__ ygb){
  int c = blockIdx.x, dbh = blockIdx.y;
  int h = dbh & 15, b = (dbh >> 4) & 1, dir = dbh >> 5;
  const unsigned short* cv = dir ? cvb : cvf;
  const unsigned short* y16 = dir ? y16b : y16f;
  unsigned short* yg = dir ? ygb : ygf;
  float Dh = (dir ? Db : Df)[h];
  int tid = threadIdx.x, lane = tid & 63, w = tid >> 6;
  int l15 = lane & 15, lhi = lane >> 4;
  __shared__ unsigned short sC [64*128];   // C[t][n]  (A)
  __shared__ unsigned short sHT[64*128];   // hT[p][n] (W)
  __shared__ float e_sh[QCH];
  size_t r0 = (size_t)b*L_SEQ + (size_t)c*QCH;
  size_t hbase = ((size_t)(dbh*NCH + c))*8192;
  if (tid < 64) e_sh[tid] = expf(acs[(size_t)dbh*L_SEQ + c*QCH + tid]);
  #pragma unroll
  for (int k = 0; k < 4; k++){
    int cid = k*256 + tid;
    int row = cid >> 4, slot = cid & 15;
    US8 uc, uh;
    uc.q = *(const uint4*)&cv[(r0+row)*CONVDIM + DINNER + DSTATE + slot*8];
    uh.q = *(const uint4*)&hin16[hbase + cid*8];
    *(uint4*)&sC [row*128 + (slot*8 ^ kx(row))] = uc.q;
    *(uint4*)&sHT[row*128 + (slot*8 ^ kx(row))] = uh.q;
  }
  __syncthreads();
  int t0 = w*16;
  bf16x8 af[4];
  #pragma unroll
  for (int ks = 0; ks < 4; ks++){
    int r = t0 + l15;
    af[ks] = *(const bf16x8*)&sC[r*128 + ((ks*32 + lhi*8) ^ kx(r))];
  }
  f32x4 acc[4];
  #pragma unroll
  for (int j = 0; j < 4; j++) acc[j] = (f32x4){0.f,0.f,0.f,0.f};
  #pragma unroll
  for (int j = 0; j < 4; j++){
    #pragma unroll
    for (int ks = 0; ks < 4; ks++){
      int r = j*16 + l15;
      bf16x8 wf = *(const bf16x8*)&sHT[r*128 + ((ks*32 + lhi*8) ^ kx(r))];
      acc[j] = __builtin_amdgcn_mfma_f32_16x16x32_bf16(af[ks], wf, acc[j], 0, 0, 0);
    }
  }
  #pragma unroll
  for (int j = 0; j < 4; j++){
    #pragma unroll
    for (int r = 0; r < 4; r++){
      int t = t0 + lhi*4 + r, p = j*16 + l15;
      size_t row = r0 + t;
      float xv = bf2f(cv[row*CONVDIM + h*HEADDIM + p]);
      float v = bf2f(y16[row*DINNER + h*HEADDIM + p]) + e_sh[t]*acc[j][r] + Dh*xv;
      yg[row*DINNER + h*HEADDIM + p] = f2bf(v);
    }
  }
}

// ---------------- gate (silu(z)) + rmsnorm, all bf16, in place on yg ----------------
__global__ void gate_norm_kernel(unsigned short* __restrict__ ygf, unsigned short* __restrict__ ygb,
                                 const unsigned short* __restrict__ z16f, const unsigned short* __restrict__ z16b,
                                 const float* __restrict__ gwf, const float* __restrict__ gwb){
  __shared__ float red[4];
  int row = blockIdx.x; int dir = blockIdx.y;
  int tid = threadIdx.x;
  unsigned short* yg = (dir ? ygb : ygf) + (size_t)row*DINNER;
  const unsigned short* z = (dir ? z16b : z16f) + (size_t)row*DINNER;
  const float* gw = dir ? gwb : gwf;
  int d = tid*4;
  US4 uy, uz;
  uy.q = *(const uint2*)&yg[d];
  uz.q = *(const uint2*)&z[d];
  float v[4]; float ss = 0.f;
  #pragma unroll
  for (int k = 0; k < 4; k++){
    float val = bf2f(uy.s[k]) * siluf(bf2f(uz.s[k]));
    v[k] = val; ss += val*val;
  }
  ss = blockReduceSum256(ss, red);   // __syncthreads inside: reads precede writes
  float scale = rsqrtf(ss*(1.f/DINNER) + 1e-5f);
  float4 w4 = *(const float4*)&gw[d];
  US4 o;
  o.s[0] = f2bf(v[0]*scale*w4.x);
  o.s[1] = f2bf(v[1]*scale*w4.y);
  o.s[2] = f2bf(v[2]*scale*w4.z);
  o.s[3] = f2bf(v[3]*scale*w4.w);
  *(uint2*)&yg[d] = o.q;
}

extern "C" void kernel_launch(void* const* d_in, const int* in_sizes, int n_in,
                              void* d_out, int out_size, void* d_ws, size_t ws_size,
                              hipStream_t stream) {
  const float* x      = (const float*)d_in[0];
  const float* norm_w = (const float*)d_in[1];
  const float* op_w   = (const float*)d_in[2];
  const float* op_b   = (const float*)d_in[3];
  const float* f_in_w    = (const float*)d_in[4];
  const float* f_conv_w  = (const float*)d_in[5];
  const float* f_conv_b  = (const float*)d_in[6];
  const float* f_dt_bias = (const float*)d_in[7];
  const float* f_A_log   = (const float*)d_in[8];
  const float* f_D       = (const float*)d_in[9];
  const float* f_gnorm_w = (const float*)d_in[10];
  const float* f_outp_w  = (const float*)d_in[11];
  const float* b_in_w    = (const float*)d_in[12];
  const float* b_conv_w  = (const float*)d_in[13];
  const float* b_conv_b  = (const float*)d_in[14];
  const float* b_dt_bias = (const float*)d_in[15];
  const float* b_A_log   = (const float*)d_in[16];
  const float* b_D       = (const float*)d_in[17];
  const float* b_gnorm_w = (const float*)d_in[18];
  const float* b_outp_w  = (const float*)d_in[19];
  float* out = (float*)d_out;

  float* ws = (float*)d_ws;
  size_t off = 0;
  unsigned short* u16f = (unsigned short*)(ws + off);
  unsigned short* u16b = u16f + (size_t)ROWS*DHALF;      off += (size_t)ROWS*DHALF;
  unsigned short* z16f = (unsigned short*)(ws + off);    off += (size_t)ROWS*DINNER/2;
  unsigned short* z16b = (unsigned short*)(ws + off);    off += (size_t)ROWS*DINNER/2;
  unsigned short* xbc16f = (unsigned short*)(ws + off);  off += (size_t)ROWS*CONVDIM/2;
  unsigned short* xbc16b = (unsigned short*)(ws + off);  off += (size_t)ROWS*CONVDIM/2;
  float* draw_f = ws + off; off += (size_t)ROWS*NHEADS;
  float* draw_b = ws + off; off += (size_t)ROWS*NHEADS;
  unsigned short* cv16f = (unsigned short*)(ws + off); off += (size_t)ROWS*CONVDIM/2;
  unsigned short* cv16b = (unsigned short*)(ws + off); off += (size_t)ROWS*CONVDIM/2;
  float* dt_f = ws + off; off += (size_t)ROWS*NHEADS;
  float* dt_b = ws + off; off += (size_t)ROWS*NHEADS;
  unsigned short* y16f = (unsigned short*)(ws + off); off += (size_t)ROWS*DINNER/2;
  unsigned short* y16b = (unsigned short*)(ws + off); off += (size_t)ROWS*DINNER/2;
  unsigned short* yg16f = (unsigned short*)(ws + off); off += (size_t)ROWS*DINNER/2;
  unsigned short* yg16b = (unsigned short*)(ws + off); off += (size_t)ROWS*DINNER/2;
  float* acs  = ws + off; off += (size_t)64*L_SEQ;
  unsigned short* S16f = (unsigned short*)(ws + off); off += (size_t)32*NCH*8192/2;
  unsigned short* S16b = (unsigned short*)(ws + off); off += (size_t)32*NCH*8192/2;
  unsigned short* hin16 = (unsigned short*)(ws + off); off += (size_t)64*NCH*8192/2;
  unsigned short* w16_fin  = (unsigned short*)(ws + off); off += (size_t)NPADIN*DHALF/2;
  unsigned short* w16_bin  = (unsigned short*)(ws + off); off += (size_t)NPADIN*DHALF/2;
  unsigned short* w16_fout = (unsigned short*)(ws + off); off += (size_t)DHALF*DINNER/2;
  unsigned short* w16_bout = (unsigned short*)(ws + off); off += (size_t)DHALF*DINNER/2;
  unsigned short* w16_op   = (unsigned short*)(ws + off); off += (size_t)DMODEL*DMODEL/2;
  // cat (bf16 [ROWS][1024]) overlays z16f+z16b region (dead after gate_norm)
  unsigned short* cat16 = z16f;

  // 1. merged prep: rmsnorm+split | weight conversions (one launch)
  {
    const int TOT = 2*NPADIN*DHALF + 2*DHALF*DINNER + DMODEL*DMODEL;
    prep_kernel<<<ROWS + TOT/4/256, 256, 0, stream>>>(
        x, norm_w, u16f, u16b,
        f_in_w, b_in_w, f_outp_w, b_outp_w, op_w,
        w16_fin, w16_bin, w16_fout, w16_bout, w16_op);
  }
  // 2. in-proj GEMM, both dirs, TM=128, single-barrier k-loop
  gemm_bf16_t<128><<<dim3(NPADIN/128, ROWS/128, 2), 256, 0, stream>>>(
      u16f, u16b, DHALF, w16_fin, w16_bin,
      nullptr, 0, nullptr, nullptr,
      z16f, z16b, DINNER,
      xbc16f, xbc16b, DINNER, CONVDIM,
      draw_f, draw_b, DINNER+CONVDIM, NHEADS,
      0, 0,
      ROWS, DINPROJ, DHALF);
  // 3. merged conv+silu | dt softplus + chunked cumsum (one launch)
  convdt_kernel<<<ROWS + 512, 320, 0, stream>>>(
      xbc16f, xbc16b, f_conv_w, f_conv_b, b_conv_w, b_conv_b, cv16f, cv16b,
      draw_f, draw_b, f_dt_bias, f_A_log, b_dt_bias, b_A_log, dt_f, dt_b, acs);
  // 4. SSD: intra (G fused in, y bf16), chunk recurrence, inter (-> bf16 yg)
  intra_kernel<<<dim3(32, 64), 256, 0, stream>>>(cv16f, cv16b, dt_f, dt_b, acs,
                                                 y16f, y16b, S16f, S16b);
  chunkscan_kernel<<<256, 256, 0, stream>>>(S16f, S16b, acs, hin16);
  inter_kernel<<<dim3(32, 64), 256, 0, stream>>>(cv16f, cv16b, acs, hin16, f_D, b_D,
                                                 y16f, y16b, yg16f, yg16b);
  // 5. gate + rmsnorm (all bf16, in place on yg)
  gate_norm_kernel<<<dim3(ROWS, 2), 256, 0, stream>>>(
      yg16f, yg16b, z16f, z16b, f_gnorm_w, b_gnorm_w);
  // 6. out-proj GEMM, both dirs -> cat16 (dir1 time-flipped, coff=512); TM=64
  gemm_bf16_t<64><<<dim3(DHALF/128, ROWS/64, 2), 256, 0, stream>>>(
      yg16f, yg16b, DINNER, w16_fout, w16_bout,
      nullptr, 0, nullptr, nullptr,
      cat16, cat16, DMODEL,
      nullptr, nullptr, 1<<30, 0,
      nullptr, nullptr, 1<<30, 0,
      DHALF, 1,
      ROWS, DHALF, DINNER);
  // 7. final projection + bias + residual (fp32 out); TM=64
  gemm_bf16_t<64><<<dim3(DMODEL/128, ROWS/64, 1), 256, 0, stream>>>(
      cat16, nullptr, DMODEL, w16_op, nullptr,
      out, DMODEL, op_b, x,
      nullptr, nullptr, 0,
      nullptr, nullptr, 1<<30, 0,
      nullptr, nullptr, 1<<30, 0,
      0, 0,
      ROWS, DMODEL, DMODEL);
}